// Round 2
// baseline (557.221 us; speedup 1.0000x reference)
//
#include <hip/hip_runtime.h>
#include <stdint.h>

typedef unsigned short u16;
typedef __attribute__((ext_vector_type(8))) short short8;
typedef __attribute__((ext_vector_type(4))) float f32x4;

#define DEVI static __device__ __forceinline__

constexpr int B = 32, R = 10, N = 512, H = 128, Q = 256, NB = 16;
constexpr int KWB = 2560;  // (DN+DR)*R

DEVI float u2f(u16 u) { union { uint32_t i; float f; } c; c.i = ((uint32_t)u) << 16; return c.f; }
DEVI u16 f2u(float f) {
  uint32_t x = __float_as_uint(f);
  uint32_t r = (x + 0x7fffu + ((x >> 16) & 1u)) >> 16;
  return (u16)r;
}

// ---------------- K-1: lin_W f32 -> bf16 (layout preserved: H x 4H, K-contiguous)
__global__ void k_cvt(const float* __restrict__ src, u16* __restrict__ dst, int n) {
  int i = blockIdx.x * 256 + threadIdx.x;
  if (i < n) dst[i] = f2u(src[i]);
}

// ---------------- K0: obs prep: obsW=bf16(obs*w_CQ), obsT=bf16 transpose, a=obs.w_C, d=obs.w_Q
__global__ void k_obs_prep(const float* __restrict__ obs, const float* __restrict__ wC,
                           const float* __restrict__ wQ, const float* __restrict__ wCQ,
                           u16* __restrict__ obsW, u16* __restrict__ obsT,
                           float* __restrict__ a_o, float* __restrict__ d_o) {
  int b = blockIdx.x / Q, o = blockIdx.x % Q;
  int t = threadIdx.x;  // 128
  long base = (long)b * Q + o;
  float x = obs[base * H + t];
  obsW[base * H + t] = f2u(x * wCQ[t]);
  obsT[((long)b * H + t) * Q + o] = f2u(x);
  float aa = x * wC[t];
  float dd = x * wQ[t];
  for (int off = 32; off; off >>= 1) { aa += __shfl_down(aa, off); dd += __shfl_down(dd, off); }
  __shared__ float sa[2], sd[2];
  if ((t & 63) == 0) { sa[t >> 6] = aa; sd[t >> 6] = dd; }
  __syncthreads();
  if (t == 0) { a_o[base] = sa[0] + sa[1]; d_o[base] = sd[0] + sd[1]; }
}

// ---------------- K1: v[b,r,k] = rf[b,r,:] . Wb[k, r*256+128 : +128]
__global__ void k_v(const float* __restrict__ rf, const float* __restrict__ Wb, float* __restrict__ v) {
  int b = blockIdx.x / R, r = blockIdx.x % R;
  int t = threadIdx.x;  // 128
  __shared__ float sm[NB][129];
  float rv = rf[((long)b * R + r) * H + t];
  for (int k = 0; k < NB; k++) sm[k][t] = rv * Wb[(long)k * KWB + r * 256 + 128 + t];
  __syncthreads();
  if (t < NB) {
    float s = 0.f;
    for (int d = 0; d < 128; d++) s += sm[t][d];
    v[((long)b * R + r) * NB + t] = s;
  }
}

// ---------------- K2: tT[b,r,k,m] = nf[b,m,:] . Wb[k, r*256 : +128] + v[b,r,k]   (bf16 out)
__global__ void k_t(const float* __restrict__ nf, const float* __restrict__ Wb,
                    const float* __restrict__ v, u16* __restrict__ tT) {
  int b = blockIdx.x / N, m = blockIdx.x % N;
  int t = threadIdx.x;  // 192 (160 active)
  __shared__ float row[128];
  if (t < 128) row[t] = nf[((long)b * N + m) * H + t];
  __syncthreads();
  if (t < 160) {
    int r = t >> 4, k = t & 15;
    const float* wp = Wb + (long)k * KWB + r * 256;
    float s = v[((long)b * R + r) * NB + k];
    for (int d = 0; d < 128; d++) s += row[d] * wp[d];
    tT[(((long)(b * R + r)) * NB + k) * N + m] = f2u(s);
  }
}

// ---------------- generic batched MFMA GEMM: C[batch](MxN) = A[batch](MxK) * Bt[batch](NxK)^T
// AF32: A is f32 in memory (converted to bf16 in-register); else bf16(u16).
template <bool AF32, bool OUTF32, bool TRANSC, bool BIAS>
__global__ __launch_bounds__(64) void gemm_bt(const void* __restrict__ Av, const u16* __restrict__ Bt,
                                              void* __restrict__ Cp, const float* __restrict__ bias,
                                              int Mdim, int Ndim, int Kdim, long sA, long sBt, long sC) {
  int batch = blockIdx.y;
  int ntn = Ndim >> 4;
  int mt = blockIdx.x / ntn, nt = blockIdx.x % ntn;
  int lane = threadIdx.x;
  int rw = lane & 15, kq = lane >> 4;
  long aoff = (long)batch * sA + (long)(mt * 16 + rw) * Kdim + kq * 8;
  const u16* bp = Bt + (long)batch * sBt + (long)(nt * 16 + rw) * Kdim + kq * 8;
  f32x4 acc = {0.f, 0.f, 0.f, 0.f};
  for (int k = 0; k < Kdim; k += 32) {
    short8 av;
    if (AF32) {
      const float* ap = (const float*)Av + aoff + k;
      float4 f0 = *(const float4*)(ap);
      float4 f1 = *(const float4*)(ap + 4);
      av[0] = (short)f2u(f0.x); av[1] = (short)f2u(f0.y);
      av[2] = (short)f2u(f0.z); av[3] = (short)f2u(f0.w);
      av[4] = (short)f2u(f1.x); av[5] = (short)f2u(f1.y);
      av[6] = (short)f2u(f1.z); av[7] = (short)f2u(f1.w);
    } else {
      av = *(const short8*)((const u16*)Av + aoff + k);
    }
    short8 bv = *(const short8*)(bp + k);
    acc = __builtin_amdgcn_mfma_f32_16x16x32_bf16(av, bv, acc, 0, 0, 0);
  }
  int gc = nt * 16 + rw;                       // col = lane&15
  float badd = BIAS ? bias[gc] : 0.f;
  for (int i = 0; i < 4; i++) {
    int gr = mt * 16 + (kq * 4 + i);           // row = (lane>>4)*4 + reg
    float val = acc[i] + badd;
    long idx = TRANSC ? ((long)gc * Mdim + gr) : ((long)gr * Ndim + gc);
    if (OUTF32) ((float*)Cp)[(long)batch * sC + idx] = val;
    else        ((u16*)Cp)[(long)batch * sC + idx] = f2u(val);
  }
}

// ---------------- K4: h = sum_r partial; nr = sigmoid(h@Ww^T + bias); nrT; b_n=nr.wQ; c_n=nr.wC
__global__ void k_nr(const float* __restrict__ part, const float* __restrict__ Ww, const float* __restrict__ rb,
                     const float* __restrict__ wC, const float* __restrict__ wQ,
                     u16* __restrict__ nr, u16* __restrict__ nrT,
                     float* __restrict__ b_n, float* __restrict__ c_n) {
  int b = blockIdx.x / N, n = blockIdx.x % N;
  int t = threadIdx.x;  // 128
  __shared__ float hs[NB];
  if (t < NB) {
    float s = 0.f;
    for (int r = 0; r < R; r++) s += part[(((long)(b * R + r)) * N + n) * NB + t];
    hs[t] = s;
  }
  __syncthreads();
  float acc = rb[0];
  for (int k = 0; k < NB; k++) acc += hs[k] * Ww[t * NB + k];
  float s = 1.f / (1.f + expf(-acc));
  nr[((long)b * N + n) * H + t] = f2u(s);
  nrT[((long)b * H + t) * N + n] = f2u(s);
  float bb = s * wQ[t], cc = s * wC[t];
  for (int off = 32; off; off >>= 1) { bb += __shfl_down(bb, off); cc += __shfl_down(cc, off); }
  __shared__ float sb[2], sc[2];
  if ((t & 63) == 0) { sb[t >> 6] = bb; sc[t >> 6] = cc; }
  __syncthreads();
  if (t == 0) { b_n[(long)b * N + n] = sb[0] + sb[1]; c_n[(long)b * N + n] = sc[0] + sc[1]; }
}

// ---------------- K6: per (b,o): max/sum over n of (b_n[n]+M) and (c_n[n]+M), node_mask
__global__ void k_rowstats(const float* __restrict__ Mm, const float* __restrict__ b_n,
                           const float* __restrict__ c_n, const float* __restrict__ nmask,
                           float* __restrict__ st1) {
  int b = blockIdx.x / Q, o = blockIdx.x % Q;
  int t = threadIdx.x;  // 256
  const float* row = Mm + ((long)b * Q + o) * N;
  float v1[2], v2[2];
  for (int i = 0; i < 2; i++) {
    int n = t + 256 * i;
    float mv = row[n];
    bool on = nmask[b * N + n] > 0.f;
    v1[i] = on ? b_n[(long)b * N + n] + mv : -1e30f;
    v2[i] = on ? c_n[(long)b * N + n] + mv : -1e30f;
  }
  float m1 = fmaxf(v1[0], v1[1]), m2 = fmaxf(v2[0], v2[1]);
  __shared__ float sm[8];
  for (int off = 32; off; off >>= 1) { m1 = fmaxf(m1, __shfl_down(m1, off)); m2 = fmaxf(m2, __shfl_down(m2, off)); }
  if ((t & 63) == 0) { sm[t >> 6] = m1; sm[4 + (t >> 6)] = m2; }
  __syncthreads();
  m1 = fmaxf(fmaxf(sm[0], sm[1]), fmaxf(sm[2], sm[3]));
  m2 = fmaxf(fmaxf(sm[4], sm[5]), fmaxf(sm[6], sm[7]));
  __syncthreads();
  float s1 = expf(v1[0] - m1) + expf(v1[1] - m1);
  float s2 = expf(v2[0] - m2) + expf(v2[1] - m2);
  for (int off = 32; off; off >>= 1) { s1 += __shfl_down(s1, off); s2 += __shfl_down(s2, off); }
  if ((t & 63) == 0) { sm[t >> 6] = s1; sm[4 + (t >> 6)] = s2; }
  __syncthreads();
  if (t == 0) {
    long idx = ((long)b * Q + o) * 4;
    st1[idx + 0] = m1; st1[idx + 1] = sm[0] + sm[1] + sm[2] + sm[3];
    st1[idx + 2] = m2; st1[idx + 3] = sm[4] + sm[5] + sm[6] + sm[7];
  }
}

// ---------------- K7: per (b,n): max/sum over o of (a_o[o]+M) and (d_o[o]+M), obs_mask
__global__ void k_colstats(const float* __restrict__ Mm, const float* __restrict__ a_o,
                           const float* __restrict__ d_o, const float* __restrict__ omask,
                           float* __restrict__ st2) {
  int b = blockIdx.x / N, n = blockIdx.x % N;
  int o = threadIdx.x;  // 256
  float mv = Mm[((long)b * Q + o) * N + n];
  bool on = omask[b * Q + o] > 0.f;
  float v1 = on ? a_o[(long)b * Q + o] + mv : -1e30f;
  float v2 = on ? d_o[(long)b * Q + o] + mv : -1e30f;
  float m1 = v1, m2 = v2;
  __shared__ float sm[8];
  for (int off = 32; off; off >>= 1) { m1 = fmaxf(m1, __shfl_down(m1, off)); m2 = fmaxf(m2, __shfl_down(m2, off)); }
  if ((o & 63) == 0) { sm[o >> 6] = m1; sm[4 + (o >> 6)] = m2; }
  __syncthreads();
  m1 = fmaxf(fmaxf(sm[0], sm[1]), fmaxf(sm[2], sm[3]));
  m2 = fmaxf(fmaxf(sm[4], sm[5]), fmaxf(sm[6], sm[7]));
  __syncthreads();
  float s1 = expf(v1 - m1);
  float s2 = expf(v2 - m2);
  for (int off = 32; off; off >>= 1) { s1 += __shfl_down(s1, off); s2 += __shfl_down(s2, off); }
  if ((o & 63) == 0) { sm[o >> 6] = s1; sm[4 + (o >> 6)] = s2; }
  __syncthreads();
  if (o == 0) {
    long idx = ((long)b * N + n) * 4;
    st2[idx + 0] = m1; st2[idx + 1] = sm[0] + sm[1] + sm[2] + sm[3];
    st2[idx + 2] = m2; st2[idx + 3] = sm[4] + sm[5] + sm[6] + sm[7];
  }
}

// ---------------- K8: sq1[o,n], sc2[o,n] (bf16) from row stats
__global__ void k_soft_row(const float* __restrict__ Mm, const float* __restrict__ b_n,
                           const float* __restrict__ c_n, const float* __restrict__ nmask,
                           const float* __restrict__ st1, u16* __restrict__ sq1, u16* __restrict__ sc2) {
  int b = blockIdx.x / Q, o = blockIdx.x % Q;
  int t = threadIdx.x;  // 256
  long ro = (long)b * Q + o;
  float m1 = st1[ro * 4], s1 = st1[ro * 4 + 1], m2 = st1[ro * 4 + 2], s2 = st1[ro * 4 + 3];
  float r1 = 1.f / s1, r2 = 1.f / s2;
  for (int i = 0; i < 2; i++) {
    int n = t + 256 * i;
    float mv = Mm[ro * N + n];
    bool on = nmask[b * N + n] > 0.f;
    float e1 = on ? expf(b_n[(long)b * N + n] + mv - m1) * r1 : 0.f;
    float e2 = on ? expf(c_n[(long)b * N + n] + mv - m2) * r2 : 0.f;
    sq1[ro * N + n] = f2u(e1);
    sc2[ro * N + n] = f2u(e2);
  }
}

// ---------------- K9: sc1T[n,o], sq2[n,o] (bf16) from col stats
__global__ void k_soft_col(const float* __restrict__ Mm, const float* __restrict__ a_o,
                           const float* __restrict__ d_o, const float* __restrict__ omask,
                           const float* __restrict__ st2, u16* __restrict__ sc1T, u16* __restrict__ sq2) {
  int b = blockIdx.x / N, n = blockIdx.x % N;
  int o = threadIdx.x;  // 256
  long rn = (long)b * N + n;
  float m1 = st2[rn * 4], s1 = st2[rn * 4 + 1], m2 = st2[rn * 4 + 2], s2 = st2[rn * 4 + 3];
  float mv = Mm[((long)b * Q + o) * N + n];
  bool on = omask[b * Q + o] > 0.f;
  float e1 = on ? expf(a_o[(long)b * Q + o] + mv - m1) / s1 : 0.f;
  float e2 = on ? expf(d_o[(long)b * Q + o] + mv - m2) / s2 : 0.f;
  sc1T[rn * Q + o] = f2u(e1);
  sq2[rn * Q + o] = f2u(e2);
}

// ---------------- K16/K17: concat [x, P, x*P, x*Qm] (bf16). XF32: X is f32 (obs) else bf16 (nr).
template <bool XF32>
__global__ void k_cat(const void* __restrict__ Xv, const u16* __restrict__ P, const u16* __restrict__ Qm,
                      u16* __restrict__ cat) {
  long base = blockIdx.x;
  int t = threadIdx.x;  // 128
  float c;
  u16 cu;
  if (XF32) { c = ((const float*)Xv)[base * H + t]; cu = f2u(c); }
  else      { cu = ((const u16*)Xv)[base * H + t]; c = u2f(cu); }
  u16 pu = P[base * H + t], qu = Qm[base * H + t];
  u16* dst = cat + base * (4 * H);
  dst[t] = cu;
  dst[H + t] = pu;
  dst[2 * H + t] = f2u(c * u2f(pu));
  dst[3 * H + t] = f2u(c * u2f(qu));
}

// ---------------- launch ----------------
extern "C" void kernel_launch(void* const* d_in, const int* in_sizes, int n_in,
                              void* d_out, int out_size, void* d_ws, size_t ws_size,
                              hipStream_t stream) {
  const float* nf    = (const float*)d_in[0];
  const float* rf    = (const float*)d_in[1];
  const float* adj   = (const float*)d_in[2];
  const float* obs   = (const float*)d_in[3];
  const float* nmask = (const float*)d_in[4];
  const float* omask = (const float*)d_in[5];
  const float* Wb    = (const float*)d_in[6];
  const float* Ww    = (const float*)d_in[7];
  const float* rb    = (const float*)d_in[8];
  const float* wC    = (const float*)d_in[9];
  const float* wQ    = (const float*)d_in[10];
  const float* wCQ   = (const float*)d_in[11];
  // d_in[12] = cq_bias: uniform shift along both softmax axes -> cancels, unused
  const float* linW  = (const float*)d_in[13];
  const float* linb  = (const float*)d_in[14];
  float* outp = (float*)d_out;

  char* w = (char*)d_ws;
  u16*   obsW = (u16*)  (w + 0);                    // 2,097,152 B
  u16*   obsT = (u16*)  (w + 2097152);              // 2,097,152
  float* a_o  = (float*)(w + 4194304);              // 32,768
  float* d_o  = (float*)(w + 4227072);              // 32,768
  float* b_n  = (float*)(w + 4259840);              // 65,536
  float* c_n  = (float*)(w + 4325376);              // 65,536
  u16*   nr   = (u16*)  (w + 4390912);              // 4,194,304
  u16*   nrT  = (u16*)  (w + 8585216);              // 4,194,304
  float* vv   = (float*)(w + 12779520);             // 20,480
  u16*   tT   = (u16*)  (w + 12800000);             // 5,242,880
  float* part = (float*)(w + 18042880);             // 10,485,760
  float* Mm   = (float*)(w + 28528640);             // 16,777,216
  float* st1  = (float*)(w + 45305856);             // 131,072
  float* st2  = (float*)(w + 45436928);             // 262,144
  u16*   sq1  = (u16*)  (w + 45699072);             // 8,388,608
  u16*   sc2  = (u16*)  (w + 54087680);             // 8,388,608
  u16*   sc1T = (u16*)  (w + 62476288);             // 8,388,608
  u16*   sq2  = (u16*)  (w + 70864896);             // 8,388,608
  u16*   P1   = (u16*)  (w + 79253504);             // 2,097,152
  u16*   T1T  = (u16*)  (w + 81350656);             // 4,194,304
  u16*   Qm1  = (u16*)  (w + 85544960);             // 2,097,152
  u16*   P2   = (u16*)  (w + 87642112);             // 4,194,304
  u16*   T2T  = (u16*)  (w + 91836416);             // 2,097,152
  u16*   Qm2  = (u16*)  (w + 93933568);             // 4,194,304
  u16*   linWb= (u16*)  (w + 98127872);             // 131,072  -> end 98,258,944
  u16*   cat1 = (u16*)  (w + 12779520);             // alias vv/tT/part (dead after k_nr / part GEMM)
  u16*   cat2 = (u16*)  (w + 28528640);             // alias Mm (dead after k_soft_*)

  k_cvt<<<(H * 4 * H + 255) / 256, 256, 0, stream>>>(linW, linWb, H * 4 * H);

  // ---- RGCN (bottleneck-first: 10x fewer FLOPs, adj read exactly once, in f32) ----
  k_obs_prep<<<B * Q, 128, 0, stream>>>(obs, wC, wQ, wCQ, obsW, obsT, a_o, d_o);
  k_v<<<B * R, 128, 0, stream>>>(rf, Wb, vv);
  k_t<<<B * N, 192, 0, stream>>>(nf, Wb, vv, tT);
  // partial[b,r,n,k] = adj[b,r] @ t[b,r]   (A = adj f32, converted in-register)
  gemm_bt<true, true, false, false><<<dim3(32, B * R), 64, 0, stream>>>(
      adj, tT, part, nullptr, N, NB, N, (long)N * N, (long)NB * N, (long)N * NB);
  k_nr<<<B * N, 128, 0, stream>>>(part, Ww, rb, wC, wQ, nr, nrT, b_n, c_n);

  // ---- shared bilinear core M = (obs .* w_CQ) @ nr^T  (f32 out) ----
  gemm_bt<false, true, false, false><<<dim3((Q / 16) * (N / 16), B), 64, 0, stream>>>(
      obsW, nr, Mm, nullptr, Q, N, H, (long)Q * H, (long)N * H, (long)Q * N);

  // ---- 4 masked softmaxes (2 row-wise, 2 col-wise) ----
  k_rowstats<<<B * Q, 256, 0, stream>>>(Mm, b_n, c_n, nmask, st1);
  k_colstats<<<B * N, 256, 0, stream>>>(Mm, a_o, d_o, omask, st2);
  k_soft_row<<<B * Q, 256, 0, stream>>>(Mm, b_n, c_n, nmask, st1, sq1, sc2);
  k_soft_col<<<B * N, 256, 0, stream>>>(Mm, a_o, d_o, omask, st2, sc1T, sq2);

  // ---- attention GEMMs (all bf16 in, bf16 out) ----
  // P1 = sq1 @ nr            (Q x H, K=N)
  gemm_bt<false, false, false, false><<<dim3((Q / 16) * (H / 16), B), 64, 0, stream>>>(
      sq1, nrT, P1, nullptr, Q, H, N, (long)Q * N, (long)H * N, (long)Q * H);
  // T1T = (sc1^T @ obs)^T    (store H x N)
  gemm_bt<false, false, true, false><<<dim3((N / 16) * (H / 16), B), 64, 0, stream>>>(
      sc1T, obsT, T1T, nullptr, N, H, Q, (long)N * Q, (long)H * Q, (long)H * N);
  // Qm1 = sq1 @ T1           (Q x H, K=N)
  gemm_bt<false, false, false, false><<<dim3((Q / 16) * (H / 16), B), 64, 0, stream>>>(
      sq1, T1T, Qm1, nullptr, Q, H, N, (long)Q * N, (long)H * N, (long)Q * H);
  // P2 = sq2 @ obs           (N x H, K=Q)
  gemm_bt<false, false, false, false><<<dim3((N / 16) * (H / 16), B), 64, 0, stream>>>(
      sq2, obsT, P2, nullptr, N, H, Q, (long)N * Q, (long)H * Q, (long)N * H);
  // T2T = (sc2 @ nr)^T       (store H x Q)
  gemm_bt<false, false, true, false><<<dim3((Q / 16) * (H / 16), B), 64, 0, stream>>>(
      sc2, nrT, T2T, nullptr, Q, H, N, (long)Q * N, (long)H * N, (long)H * Q);
  // Qm2 = sq2 @ T2           (N x H, K=Q)
  gemm_bt<false, false, false, false><<<dim3((N / 16) * (H / 16), B), 64, 0, stream>>>(
      sq2, T2T, Qm2, nullptr, N, H, Q, (long)N * Q, (long)H * Q, (long)N * H);

  // ---- concat + output linear (f32 out to d_out) ----
  k_cat<true ><<<B * Q, 128, 0, stream>>>(obs, P1, Qm1, cat1);
  k_cat<false><<<B * N, 128, 0, stream>>>(nr, P2, Qm2, cat2);
  gemm_bt<false, true, false, true><<<dim3((Q / 16) * (H / 16), B), 64, 0, stream>>>(
      cat1, linWb, outp, linb, Q, H, 4 * H, (long)Q * 4 * H, 0L, (long)Q * H);
  gemm_bt<false, true, false, true><<<dim3((N / 16) * (H / 16), B), 64, 0, stream>>>(
      cat2, linWb, outp + (long)B * Q * H, linb, N, H, 4 * H, (long)N * 4 * H, 0L, (long)N * H);

  (void)in_sizes; (void)n_in; (void)out_size; (void)ws_size;
}

// Round 3
// 371.283 us; speedup vs baseline: 1.5008x; 1.5008x over previous
//
#include <hip/hip_runtime.h>
#include <hip/hip_bf16.h>
#include <stdint.h>

typedef unsigned short u16;
typedef __attribute__((ext_vector_type(8))) short short8;
typedef __attribute__((ext_vector_type(4))) float f32x4;

#define DEVI static __device__ __forceinline__

constexpr int B = 32, R = 10, N = 512, H = 128, Q = 256, NB = 16;
constexpr int KWB = 2560;  // (DN+DR)*R

DEVI u16 f2u(float f) { return __builtin_bit_cast(unsigned short, __float2bfloat16(f)); }
DEVI float u2f(u16 u) { union { uint32_t i; float f; } c; c.i = ((uint32_t)u) << 16; return c.f; }

DEVI float wredmax(float v) { for (int o = 32; o; o >>= 1) v = fmaxf(v, __shfl_xor(v, o)); return v; }
DEVI float wredsum(float v) { for (int o = 32; o; o >>= 1) v += __shfl_xor(v, o); return v; }

// ---------------- vectorized f32 -> bf16 convert (n4 = elems/4)
__global__ void k_cvt4(const float* __restrict__ src, u16* __restrict__ dst, int n4) {
  int i = blockIdx.x * 256 + threadIdx.x;
  if (i >= n4) return;
  float4 f = ((const float4*)src)[i];
  ushort4 o;
  o.x = f2u(f.x); o.y = f2u(f.y); o.z = f2u(f.z); o.w = f2u(f.w);
  ((ushort4*)dst)[i] = o;
}

// ---------------- WbB[r][k][d] = bf16(Wb[k][r*256+d]), d<128
__global__ void k_wb(const float* __restrict__ Wb, u16* __restrict__ WbB) {
  int rk = blockIdx.x;  // r*NB + k
  int r = rk / NB, k = rk % NB;
  int t = threadIdx.x;  // 128
  WbB[(long)rk * 128 + t] = f2u(Wb[(long)k * KWB + r * 256 + t]);
}

// ---------------- v[b,r,k] = rf[b,r,:] . Wb[k, r*256+128 : +128]
__global__ void k_v(const float* __restrict__ rf, const float* __restrict__ Wb, float* __restrict__ v) {
  int b = blockIdx.x / R, r = blockIdx.x % R;
  int t = threadIdx.x;  // 128
  __shared__ float sm[NB][129];
  float rv = rf[((long)b * R + r) * H + t];
  for (int k = 0; k < NB; k++) sm[k][t] = rv * Wb[(long)k * KWB + r * 256 + 128 + t];
  __syncthreads();
  if (t < NB) {
    float s = 0.f;
    for (int d = 0; d < 128; d++) s += sm[t][d];
    v[((long)b * R + r) * NB + t] = s;
  }
}

// ---------------- obs prep: obsW = bf16(obs*w_CQ), a_o = obs.w_C, d_o = obs.w_Q
__global__ void k_obs_prep(const float* __restrict__ obs, const float* __restrict__ wC,
                           const float* __restrict__ wQ, const float* __restrict__ wCQ,
                           u16* __restrict__ obsW, float* __restrict__ a_o, float* __restrict__ d_o) {
  int b = blockIdx.x / Q, o = blockIdx.x % Q;
  int t = threadIdx.x;  // 128
  long base = (long)b * Q + o;
  float x = obs[base * H + t];
  obsW[base * H + t] = f2u(x * wCQ[t]);
  float aa = wredsum(x * wC[t]);
  float dd = wredsum(x * wQ[t]);
  __shared__ float sa[2], sd[2];
  if ((t & 63) == 0) { sa[t >> 6] = aa; sd[t >> 6] = dd; }
  __syncthreads();
  if (t == 0) { a_o[base] = sa[0] + sa[1]; d_o[base] = sd[0] + sd[1]; }
}

// ---------------- tiled transpose: in[batch][Rr][Cc] -> out[batch][Cc][Rr] (bf16 out)
template <bool INF32>
__global__ void k_transpose(const void* __restrict__ in, u16* __restrict__ out, int Rr, int Cc) {
  __shared__ u16 tile[32][33];
  int batch = blockIdx.z;
  int c0 = blockIdx.x * 32, r0 = blockIdx.y * 32;
  int tx = threadIdx.x, ty = threadIdx.y;  // 32 x 8
  for (int i = 0; i < 4; i++) {
    int r = r0 + ty + i * 8, c = c0 + tx;
    if (INF32) tile[ty + i * 8][tx] = f2u(((const float*)in)[((long)batch * Rr + r) * Cc + c]);
    else       tile[ty + i * 8][tx] = ((const u16*)in)[((long)batch * Rr + r) * Cc + c];
  }
  __syncthreads();
  for (int i = 0; i < 4; i++) {
    int c = c0 + ty + i * 8, r = r0 + tx;
    out[((long)batch * Cc + c) * Rr + r] = tile[tx][ty + i * 8];
  }
}

// ---------------- generic batched MFMA GEMM: C[batch](MxN) = A[batch](MxK) * Bt[batch](NxK)^T
// AF32: A f32 in memory (cvt in-register). CMODE: 0 bf16 C, 1 f32 C, 2 dual f32 (C + C^T).
// BMODE: 0 none, 1 col bias[gc], 2 row bias[batch*NB+gr]. RGRID: batch -> (a = batch%R, b = batch/R).
template <bool AF32, int CMODE, bool TRANSC, int BMODE, bool RGRID>
__global__ __launch_bounds__(64) void gemm_bt(const void* __restrict__ Av, const u16* __restrict__ Bt,
                                              void* __restrict__ Cp, float* __restrict__ C2,
                                              const float* __restrict__ bias,
                                              int Mdim, int Ndim, int Kdim,
                                              long sA, long sBt, long sC, long sC2) {
  int batch = blockIdx.y;
  int ab = batch, bb = batch;
  if (RGRID) { ab = batch % R; bb = batch / R; }
  int ntn = Ndim >> 4;
  int mt = blockIdx.x / ntn, nt = blockIdx.x % ntn;
  int lane = threadIdx.x;
  int rw = lane & 15, kq = lane >> 4;
  long aoff = (long)ab * sA + (long)(mt * 16 + rw) * Kdim + kq * 8;
  const u16* bp = Bt + (long)bb * sBt + (long)(nt * 16 + rw) * Kdim + kq * 8;
  f32x4 acc = {0.f, 0.f, 0.f, 0.f};
#pragma unroll 2
  for (int k = 0; k < Kdim; k += 32) {
    short8 av;
    if (AF32) {
      const float* ap = (const float*)Av + aoff + k;
      float4 f0 = *(const float4*)(ap);
      float4 f1 = *(const float4*)(ap + 4);
      av[0] = (short)f2u(f0.x); av[1] = (short)f2u(f0.y);
      av[2] = (short)f2u(f0.z); av[3] = (short)f2u(f0.w);
      av[4] = (short)f2u(f1.x); av[5] = (short)f2u(f1.y);
      av[6] = (short)f2u(f1.z); av[7] = (short)f2u(f1.w);
    } else {
      av = *(const short8*)((const u16*)Av + aoff + k);
    }
    short8 bv = *(const short8*)(bp + k);
    acc = __builtin_amdgcn_mfma_f32_16x16x32_bf16(av, bv, acc, 0, 0, 0);
  }
  int gc = nt * 16 + rw;  // col = lane&15
  float cb = (BMODE == 1) ? bias[gc] : 0.f;
  for (int i = 0; i < 4; i++) {
    int gr = mt * 16 + (kq * 4 + i);  // row = (lane>>4)*4 + reg
    float val = acc[i] + cb;
    if (BMODE == 2) val += bias[(long)batch * NB + gr];
    if (CMODE == 2) {
      ((float*)Cp)[(long)batch * sC + (long)gr * Ndim + gc] = val;
      C2[(long)batch * sC2 + (long)gc * Mdim + gr] = val;
    } else {
      long idx = TRANSC ? ((long)gc * Mdim + gr) : ((long)gr * Ndim + gc);
      if (CMODE == 1) ((float*)Cp)[(long)batch * sC + idx] = val;
      else            ((u16*)Cp)[(long)batch * sC + idx] = f2u(val);
    }
  }
}

// ---------------- h = sum_r part; nr = sigmoid(h@Ww^T + rb); b_n = nr.wQ; c_n = nr.wC
__global__ void k_nr(const float* __restrict__ part, const float* __restrict__ Ww, const float* __restrict__ rb,
                     const float* __restrict__ wC, const float* __restrict__ wQ,
                     u16* __restrict__ nr, float* __restrict__ b_n, float* __restrict__ c_n) {
  int b = blockIdx.x / N, n = blockIdx.x % N;
  int t = threadIdx.x;  // 128
  __shared__ float hs[NB];
  if (t < NB) {
    float s = 0.f;
    for (int r = 0; r < R; r++) s += part[(((long)(b * R + r)) * N + n) * NB + t];
    hs[t] = s;
  }
  __syncthreads();
  float acc = rb[0];
  for (int k = 0; k < NB; k++) acc += hs[k] * Ww[t * NB + k];
  float s = 1.f / (1.f + expf(-acc));
  nr[((long)b * N + n) * H + t] = f2u(s);
  float bb = wredsum(s * wQ[t]), cc = wredsum(s * wC[t]);
  __shared__ float sb[2], sc[2];
  if ((t & 63) == 0) { sb[t >> 6] = bb; sc[t >> 6] = cc; }
  __syncthreads();
  if (t == 0) { b_n[(long)b * N + n] = sb[0] + sb[1]; c_n[(long)b * N + n] = sc[0] + sc[1]; }
}

// ---------------- fused row softmax: per (b,o) read Mm row once -> sq1, sc2
__global__ void k_soft_row2(const float* __restrict__ Mm, const float* __restrict__ b_n,
                            const float* __restrict__ c_n, const float* __restrict__ nmask,
                            u16* __restrict__ sq1, u16* __restrict__ sc2) {
  int b = blockIdx.x / Q, o = blockIdx.x % Q;
  int t = threadIdx.x;  // 256
  long ro = (long)b * Q + o;
  float v1[2], v2[2];
  for (int i = 0; i < 2; i++) {
    int n = t + 256 * i;
    float mv = Mm[ro * N + n];
    bool on = nmask[(long)b * N + n] > 0.f;
    v1[i] = on ? b_n[(long)b * N + n] + mv : -1e30f;
    v2[i] = on ? c_n[(long)b * N + n] + mv : -1e30f;
  }
  __shared__ float s1a[4], s2a[4];
  float m1 = wredmax(fmaxf(v1[0], v1[1]));
  float m2 = wredmax(fmaxf(v2[0], v2[1]));
  int wv = t >> 6;
  if ((t & 63) == 0) { s1a[wv] = m1; s2a[wv] = m2; }
  __syncthreads();
  m1 = fmaxf(fmaxf(s1a[0], s1a[1]), fmaxf(s1a[2], s1a[3]));
  m2 = fmaxf(fmaxf(s2a[0], s2a[1]), fmaxf(s2a[2], s2a[3]));
  __syncthreads();
  float e1[2], e2[2];
  e1[0] = expf(v1[0] - m1); e1[1] = expf(v1[1] - m1);
  e2[0] = expf(v2[0] - m2); e2[1] = expf(v2[1] - m2);
  float s1 = wredsum(e1[0] + e1[1]);
  float s2 = wredsum(e2[0] + e2[1]);
  if ((t & 63) == 0) { s1a[wv] = s1; s2a[wv] = s2; }
  __syncthreads();
  float r1 = 1.f / (s1a[0] + s1a[1] + s1a[2] + s1a[3]);
  float r2 = 1.f / (s2a[0] + s2a[1] + s2a[2] + s2a[3]);
  for (int i = 0; i < 2; i++) {
    int n = t + 256 * i;
    sq1[ro * N + n] = f2u(e1[i] * r1);
    sc2[ro * N + n] = f2u(e2[i] * r2);
  }
}

// ---------------- fused col softmax: per (b,n) read MmT row once -> sc1T, sq2
__global__ void k_soft_col2(const float* __restrict__ MmT, const float* __restrict__ a_o,
                            const float* __restrict__ d_o, const float* __restrict__ omask,
                            u16* __restrict__ sc1T, u16* __restrict__ sq2) {
  int b = blockIdx.x / N, n = blockIdx.x % N;
  int o = threadIdx.x;  // 256
  long rn = (long)b * N + n;
  float mv = MmT[rn * Q + o];
  bool on = omask[(long)b * Q + o] > 0.f;
  float v1 = on ? a_o[(long)b * Q + o] + mv : -1e30f;
  float v2 = on ? d_o[(long)b * Q + o] + mv : -1e30f;
  __shared__ float s1a[4], s2a[4];
  float m1 = wredmax(v1), m2 = wredmax(v2);
  int wv = o >> 6;
  if ((o & 63) == 0) { s1a[wv] = m1; s2a[wv] = m2; }
  __syncthreads();
  m1 = fmaxf(fmaxf(s1a[0], s1a[1]), fmaxf(s1a[2], s1a[3]));
  m2 = fmaxf(fmaxf(s2a[0], s2a[1]), fmaxf(s2a[2], s2a[3]));
  __syncthreads();
  float e1 = expf(v1 - m1), e2 = expf(v2 - m2);
  float s1 = wredsum(e1), s2 = wredsum(e2);
  if ((o & 63) == 0) { s1a[wv] = s1; s2a[wv] = s2; }
  __syncthreads();
  float r1 = 1.f / (s1a[0] + s1a[1] + s1a[2] + s1a[3]);
  float r2 = 1.f / (s2a[0] + s2a[1] + s2a[2] + s2a[3]);
  sc1T[rn * Q + o] = f2u(e1 * r1);
  sq2[rn * Q + o] = f2u(e2 * r2);
}

// ---------------- concat [x, P, x*P, x*Qm] (bf16). XF32: X f32 (obs) else bf16 (nr).
template <bool XF32>
__global__ void k_cat(const void* __restrict__ Xv, const u16* __restrict__ P, const u16* __restrict__ Qm,
                      u16* __restrict__ cat) {
  long base = blockIdx.x;
  int t = threadIdx.x;  // 128
  float c;
  u16 cu;
  if (XF32) { c = ((const float*)Xv)[base * H + t]; cu = f2u(c); }
  else      { cu = ((const u16*)Xv)[base * H + t]; c = u2f(cu); }
  u16 pu = P[base * H + t], qu = Qm[base * H + t];
  u16* dst = cat + base * (4 * H);
  dst[t] = cu;
  dst[H + t] = pu;
  dst[2 * H + t] = f2u(c * u2f(pu));
  dst[3 * H + t] = f2u(c * u2f(qu));
}

// ---------------- launch ----------------
extern "C" void kernel_launch(void* const* d_in, const int* in_sizes, int n_in,
                              void* d_out, int out_size, void* d_ws, size_t ws_size,
                              hipStream_t stream) {
  const float* nf    = (const float*)d_in[0];
  const float* rf    = (const float*)d_in[1];
  const float* adj   = (const float*)d_in[2];
  const float* obs   = (const float*)d_in[3];
  const float* nmask = (const float*)d_in[4];
  const float* omask = (const float*)d_in[5];
  const float* Wb    = (const float*)d_in[6];
  const float* Ww    = (const float*)d_in[7];
  const float* rb    = (const float*)d_in[8];
  const float* wC    = (const float*)d_in[9];
  const float* wQ    = (const float*)d_in[10];
  const float* wCQ   = (const float*)d_in[11];
  // d_in[12] = cq_bias: uniform shift along both softmax axes -> cancels, unused
  const float* linW  = (const float*)d_in[13];
  const float* linb  = (const float*)d_in[14];
  float* outp = (float*)d_out;

  char* w = (char*)d_ws;
  auto alloc = [&](size_t bytes) { char* p = w; w += (bytes + 255) & ~(size_t)255; return p; };
  u16*   linWb = (u16*)  alloc((size_t)H * 4 * H * 2);
  u16*   nfB   = (u16*)  alloc((size_t)B * N * H * 2);
  u16*   WbB   = (u16*)  alloc((size_t)R * NB * 128 * 2);
  float* vv    = (float*)alloc((size_t)B * R * NB * 4);
  u16*   obsW  = (u16*)  alloc((size_t)B * Q * H * 2);
  u16*   obsT  = (u16*)  alloc((size_t)B * H * Q * 2);
  float* a_o   = (float*)alloc((size_t)B * Q * 4);
  float* d_o   = (float*)alloc((size_t)B * Q * 4);
  float* b_n   = (float*)alloc((size_t)B * N * 4);
  float* c_n   = (float*)alloc((size_t)B * N * 4);
  u16*   nr    = (u16*)  alloc((size_t)B * N * H * 2);
  u16*   nrT   = (u16*)  alloc((size_t)B * H * N * 2);
  u16*   tT    = (u16*)  alloc((size_t)B * R * NB * N * 2);
  float* part  = (float*)alloc((size_t)B * R * N * NB * 4);
  float* Mm    = (float*)alloc((size_t)B * Q * N * 4);
  float* MmT   = (float*)alloc((size_t)B * N * Q * 4);
  u16*   sq1   = (u16*)  alloc((size_t)B * Q * N * 2);
  u16*   sc2   = (u16*)  alloc((size_t)B * Q * N * 2);
  u16*   sc1T  = (u16*)  alloc((size_t)B * N * Q * 2);
  u16*   sq2   = (u16*)  alloc((size_t)B * N * Q * 2);
  u16*   P1    = (u16*)  alloc((size_t)B * Q * H * 2);
  u16*   T1T   = (u16*)  alloc((size_t)B * H * N * 2);
  u16*   Qm1   = (u16*)  alloc((size_t)B * Q * H * 2);
  u16*   P2    = (u16*)  alloc((size_t)B * N * H * 2);
  u16*   T2T   = (u16*)  alloc((size_t)B * H * Q * 2);
  u16*   Qm2   = (u16*)  alloc((size_t)B * N * H * 2);
  u16*   cat1  = (u16*)  alloc((size_t)B * Q * 4 * H * 2);
  u16*   cat2  = (u16*)  alloc((size_t)B * N * 4 * H * 2);

  // ---- one-time converts / prep ----
  k_cvt4<<<(H * 4 * H / 4 + 255) / 256, 256, 0, stream>>>(linW, linWb, H * 4 * H / 4);
  k_cvt4<<<(B * N * H / 4 + 255) / 256, 256, 0, stream>>>(nf, nfB, B * N * H / 4);
  k_wb<<<R * NB, 128, 0, stream>>>(Wb, WbB);
  k_v<<<B * R, 128, 0, stream>>>(rf, Wb, vv);
  k_obs_prep<<<B * Q, 128, 0, stream>>>(obs, wC, wQ, wCQ, obsW, a_o, d_o);
  k_transpose<true><<<dim3(H / 32, Q / 32, B), dim3(32, 8), 0, stream>>>(obs, obsT, Q, H);

  // ---- RGCN ----
  // tT[b,r](16 x N) = WbB[r](16 x 128) @ nfB[b]^T + v[b,r]  (row bias)
  gemm_bt<false, 0, false, 2, true><<<dim3(N / 16, B * R), 64, 0, stream>>>(
      WbB, nfB, tT, nullptr, vv, NB, N, H, (long)NB * 128, (long)N * H, (long)NB * N, 0);
  // part[b,r](N x 16) = adj[b,r] @ tT[b,r]^T   (adj f32, cvt in-register)
  gemm_bt<true, 1, false, 0, false><<<dim3(N / 16, B * R), 64, 0, stream>>>(
      adj, tT, part, nullptr, nullptr, N, NB, N, (long)N * N, (long)NB * N, (long)N * NB, 0);
  k_nr<<<B * N, 128, 0, stream>>>(part, Ww, rb, wC, wQ, nr, b_n, c_n);
  k_transpose<false><<<dim3(H / 32, N / 32, B), dim3(32, 8), 0, stream>>>(nr, nrT, N, H);

  // ---- bilinear core M = (obs .* w_CQ) @ nr^T, dual f32 out (Mm + MmT) ----
  gemm_bt<false, 2, false, 0, false><<<dim3((Q / 16) * (N / 16), B), 64, 0, stream>>>(
      obsW, nr, Mm, MmT, nullptr, Q, N, H, (long)Q * H, (long)N * H, (long)Q * N, (long)N * Q);

  // ---- fused masked softmaxes ----
  k_soft_row2<<<B * Q, 256, 0, stream>>>(Mm, b_n, c_n, nmask, sq1, sc2);
  k_soft_col2<<<B * N, 256, 0, stream>>>(MmT, a_o, d_o, omask, sc1T, sq2);

  // ---- attention GEMMs (bf16 in/out) ----
  gemm_bt<false, 0, false, 0, false><<<dim3((Q / 16) * (H / 16), B), 64, 0, stream>>>(
      sq1, nrT, P1, nullptr, nullptr, Q, H, N, (long)Q * N, (long)H * N, (long)Q * H, 0);
  gemm_bt<false, 0, true, 0, false><<<dim3((N / 16) * (H / 16), B), 64, 0, stream>>>(
      sc1T, obsT, T1T, nullptr, nullptr, N, H, Q, (long)N * Q, (long)H * Q, (long)H * N, 0);
  gemm_bt<false, 0, false, 0, false><<<dim3((Q / 16) * (H / 16), B), 64, 0, stream>>>(
      sq1, T1T, Qm1, nullptr, nullptr, Q, H, N, (long)Q * N, (long)H * N, (long)Q * H, 0);
  gemm_bt<false, 0, false, 0, false><<<dim3((N / 16) * (H / 16), B), 64, 0, stream>>>(
      sq2, obsT, P2, nullptr, nullptr, N, H, Q, (long)N * Q, (long)H * Q, (long)N * H, 0);
  gemm_bt<false, 0, true, 0, false><<<dim3((Q / 16) * (H / 16), B), 64, 0, stream>>>(
      sc2, nrT, T2T, nullptr, nullptr, Q, H, N, (long)Q * N, (long)H * N, (long)H * Q, 0);
  gemm_bt<false, 0, false, 0, false><<<dim3((N / 16) * (H / 16), B), 64, 0, stream>>>(
      sq2, T2T, Qm2, nullptr, nullptr, N, H, Q, (long)N * Q, (long)H * Q, (long)N * H, 0);

  // ---- concat + output linear (f32 out) ----
  k_cat<true ><<<B * Q, 128, 0, stream>>>(obs, P1, Qm1, cat1);
  k_cat<false><<<B * N, 128, 0, stream>>>(nr, P2, Qm2, cat2);
  gemm_bt<false, 1, false, 1, false><<<dim3((Q / 16) * (H / 16), B), 64, 0, stream>>>(
      cat1, linWb, outp, nullptr, linb, Q, H, 4 * H, (long)Q * 4 * H, 0L, (long)Q * H, 0);
  gemm_bt<false, 1, false, 1, false><<<dim3((N / 16) * (H / 16), B), 64, 0, stream>>>(
      cat2, linWb, outp + (long)B * Q * H, nullptr, linb, N, H, 4 * H, (long)N * 4 * H, 0L, (long)N * H, 0);

  (void)in_sizes; (void)n_in; (void)out_size; (void)ws_size;
}

// Round 4
// 357.558 us; speedup vs baseline: 1.5584x; 1.0384x over previous
//
#include <hip/hip_runtime.h>
#include <hip/hip_bf16.h>
#include <stdint.h>

typedef unsigned short u16;
typedef __attribute__((ext_vector_type(8))) short short8;
typedef __attribute__((ext_vector_type(4))) float f32x4;

#define DEVI static __device__ __forceinline__

constexpr int B = 32, R = 10, N = 512, H = 128, Q = 256, NB = 16;
constexpr int KWB = 2560;  // (DN+DR)*R

DEVI u16 f2u(float f) { return __builtin_bit_cast(unsigned short, __float2bfloat16(f)); }
DEVI float u2f(u16 u) { union { uint32_t i; float f; } c; c.i = ((uint32_t)u) << 16; return c.f; }

DEVI float wredmax(float v) { for (int o = 32; o; o >>= 1) v = fmaxf(v, __shfl_xor(v, o)); return v; }
DEVI float wredsum(float v) { for (int o = 32; o; o >>= 1) v += __shfl_xor(v, o); return v; }

// ---------------- prep: linW f32->bf16 (blocks 0..63), WbB slices (blocks 64..143)
__global__ void k_prep_w(const float* __restrict__ linW, u16* __restrict__ linWb,
                         const float* __restrict__ Wb, u16* __restrict__ WbB) {
  int bid = blockIdx.x, t = threadIdx.x;  // 256
  if (bid < 64) {
    int i = bid * 256 + t;  // n4 = 16384
    float4 f = ((const float4*)linW)[i];
    ushort4 o;
    o.x = f2u(f.x); o.y = f2u(f.y); o.z = f2u(f.z); o.w = f2u(f.w);
    ((ushort4*)linWb)[i] = o;
  } else {
    int rk = (bid - 64) * 2 + (t >> 7);  // 160 slices
    int d = t & 127;
    int r = rk / NB, k = rk % NB;
    WbB[(long)rk * 128 + d] = f2u(Wb[(long)k * KWB + r * 256 + d]);
  }
}

// ---------------- v[b,r,k] = rf[b,r,:] . Wb[k, r*256+128 : +128]
__global__ void k_v(const float* __restrict__ rf, const float* __restrict__ Wb, float* __restrict__ v) {
  int b = blockIdx.x / R, r = blockIdx.x % R;
  int t = threadIdx.x;  // 128
  __shared__ float sm[NB][129];
  float rv = rf[((long)b * R + r) * H + t];
  for (int k = 0; k < NB; k++) sm[k][t] = rv * Wb[(long)k * KWB + r * 256 + 128 + t];
  __syncthreads();
  if (t < NB) {
    float s = 0.f;
    for (int d = 0; d < 128; d++) s += sm[t][d];
    v[((long)b * R + r) * NB + t] = s;
  }
}

// ---------------- obs prep: obsW = bf16(obs*w_CQ), a_o = obs.w_C, d_o = obs.w_Q
__global__ void k_obs_prep(const float* __restrict__ obs, const float* __restrict__ wC,
                           const float* __restrict__ wQ, const float* __restrict__ wCQ,
                           u16* __restrict__ obsW, float* __restrict__ a_o, float* __restrict__ d_o) {
  int b = blockIdx.x / Q, o = blockIdx.x % Q;
  int t = threadIdx.x;  // 128
  long base = (long)b * Q + o;
  float x = obs[base * H + t];
  obsW[base * H + t] = f2u(x * wCQ[t]);
  float aa = wredsum(x * wC[t]);
  float dd = wredsum(x * wQ[t]);
  __shared__ float sa[2], sd[2];
  if ((t & 63) == 0) { sa[t >> 6] = aa; sd[t >> 6] = dd; }
  __syncthreads();
  if (t == 0) { a_o[base] = sa[0] + sa[1]; d_o[base] = sd[0] + sd[1]; }
}

// ---------------- tiled transpose: in[batch][Rr][Cc] -> out[batch][Cc][Rr] (bf16 out)
template <bool INF32>
__global__ void k_transpose(const void* __restrict__ in, u16* __restrict__ out, int Rr, int Cc) {
  __shared__ u16 tile[32][33];
  int batch = blockIdx.z;
  int c0 = blockIdx.x * 32, r0 = blockIdx.y * 32;
  int tx = threadIdx.x, ty = threadIdx.y;  // 32 x 8
  for (int i = 0; i < 4; i++) {
    int r = r0 + ty + i * 8, c = c0 + tx;
    if (INF32) tile[ty + i * 8][tx] = f2u(((const float*)in)[((long)batch * Rr + r) * Cc + c]);
    else       tile[ty + i * 8][tx] = ((const u16*)in)[((long)batch * Rr + r) * Cc + c];
  }
  __syncthreads();
  for (int i = 0; i < 4; i++) {
    int c = c0 + ty + i * 8, r = r0 + tx;
    out[((long)batch * Cc + c) * Rr + r] = tile[tx][ty + i * 8];
  }
}

// ---------------- generic batched MFMA GEMM: C[batch](MxN) = A[batch](MxK) * Bt[batch](NxK)^T
// AF32/BF32: operand f32 in memory (cvt in-register). CMODE: 0 bf16 C, 1 f32 C, 2 dual f32 (C + C^T).
// BMODE: 0 none, 1 col bias[gc], 2 row bias[batch*NB+gr]. RGRID: batch -> (a = batch%R, b = batch/R).
template <bool AF32, bool BF32, int CMODE, bool TRANSC, int BMODE, bool RGRID, int UNROLL>
__global__ __launch_bounds__(64) void gemm_bt(const void* __restrict__ Av, const void* __restrict__ Btv,
                                              void* __restrict__ Cp, float* __restrict__ C2,
                                              const float* __restrict__ bias,
                                              int Mdim, int Ndim, int Kdim,
                                              long sA, long sBt, long sC, long sC2) {
  int batch = blockIdx.y;
  int ab = batch, bb = batch;
  if (RGRID) { ab = batch % R; bb = batch / R; }
  int ntn = Ndim >> 4;
  int mt = blockIdx.x / ntn, nt = blockIdx.x % ntn;
  int lane = threadIdx.x;
  int rw = lane & 15, kq = lane >> 4;
  long aoff = (long)ab * sA + (long)(mt * 16 + rw) * Kdim + kq * 8;
  long boff = (long)bb * sBt + (long)(nt * 16 + rw) * Kdim + kq * 8;
  f32x4 acc = {0.f, 0.f, 0.f, 0.f};
#pragma unroll UNROLL
  for (int k = 0; k < Kdim; k += 32) {
    short8 av, bv;
    if (AF32) {
      const float* ap = (const float*)Av + aoff + k;
      float4 f0 = *(const float4*)(ap);
      float4 f1 = *(const float4*)(ap + 4);
      av[0] = (short)f2u(f0.x); av[1] = (short)f2u(f0.y);
      av[2] = (short)f2u(f0.z); av[3] = (short)f2u(f0.w);
      av[4] = (short)f2u(f1.x); av[5] = (short)f2u(f1.y);
      av[6] = (short)f2u(f1.z); av[7] = (short)f2u(f1.w);
    } else {
      av = *(const short8*)((const u16*)Av + aoff + k);
    }
    if (BF32) {
      const float* bp = (const float*)Btv + boff + k;
      float4 f0 = *(const float4*)(bp);
      float4 f1 = *(const float4*)(bp + 4);
      bv[0] = (short)f2u(f0.x); bv[1] = (short)f2u(f0.y);
      bv[2] = (short)f2u(f0.z); bv[3] = (short)f2u(f0.w);
      bv[4] = (short)f2u(f1.x); bv[5] = (short)f2u(f1.y);
      bv[6] = (short)f2u(f1.z); bv[7] = (short)f2u(f1.w);
    } else {
      bv = *(const short8*)((const u16*)Btv + boff + k);
    }
    acc = __builtin_amdgcn_mfma_f32_16x16x32_bf16(av, bv, acc, 0, 0, 0);
  }
  int gc = nt * 16 + rw;  // col = lane&15
  float cb = (BMODE == 1) ? bias[gc] : 0.f;
  for (int i = 0; i < 4; i++) {
    int gr = mt * 16 + (kq * 4 + i);  // row = (lane>>4)*4 + reg
    float val = acc[i] + cb;
    if (BMODE == 2) val += bias[(long)batch * NB + gr];
    if (CMODE == 2) {
      ((float*)Cp)[(long)batch * sC + (long)gr * Ndim + gc] = val;
      C2[(long)batch * sC2 + (long)gc * Mdim + gr] = val;
    } else {
      long idx = TRANSC ? ((long)gc * Mdim + gr) : ((long)gr * Ndim + gc);
      if (CMODE == 1) ((float*)Cp)[(long)batch * sC + idx] = val;
      else            ((u16*)Cp)[(long)batch * sC + idx] = f2u(val);
    }
  }
}

// ---------------- z-multiplexed bf16 GEMMs (shapes/operands per z), C bf16
struct GPar {
  const u16* A; const u16* Bt; u16* C;
  int Mdim; int Kdim; long sA, sBt, sC; int tc;
};
__global__ __launch_bounds__(64) void gemm_quad(GPar p0, GPar p1, GPar p2, GPar p3, int Ndim) {
  int z = blockIdx.z;
  GPar p = (z == 0) ? p0 : (z == 1) ? p1 : (z == 2) ? p2 : p3;
  int batch = blockIdx.y;
  int ntn = Ndim >> 4;
  int mt = blockIdx.x / ntn, nt = blockIdx.x % ntn;
  if (mt * 16 >= p.Mdim) return;
  int lane = threadIdx.x;
  int rw = lane & 15, kq = lane >> 4;
  const u16* ap = p.A + (long)batch * p.sA + (long)(mt * 16 + rw) * p.Kdim + kq * 8;
  const u16* bp = p.Bt + (long)batch * p.sBt + (long)(nt * 16 + rw) * p.Kdim + kq * 8;
  f32x4 acc = {0.f, 0.f, 0.f, 0.f};
#pragma unroll 2
  for (int k = 0; k < p.Kdim; k += 32) {
    short8 av = *(const short8*)(ap + k);
    short8 bv = *(const short8*)(bp + k);
    acc = __builtin_amdgcn_mfma_f32_16x16x32_bf16(av, bv, acc, 0, 0, 0);
  }
  int gc = nt * 16 + rw;
  for (int i = 0; i < 4; i++) {
    int gr = mt * 16 + (kq * 4 + i);
    long idx = p.tc ? ((long)gc * p.Mdim + gr) : ((long)gr * Ndim + gc);
    p.C[(long)batch * p.sC + idx] = f2u(acc[i]);
  }
}

// ---------------- fused concat+output GEMM: out = [X,P,X*P,X*Qm] @ linWb^T + linb  (f32 out)
// A-row assembled in-register; K=512, section = k>>7 (wave-uniform).
template <bool XF32>
__global__ __launch_bounds__(64) void gemm_cat(const void* __restrict__ Xv, const u16* __restrict__ P,
                                               const u16* __restrict__ Qm, const u16* __restrict__ Wt,
                                               const float* __restrict__ bias, float* __restrict__ out,
                                               int Mdim) {
  int batch = blockIdx.y;
  int ntn = H >> 4;  // 8
  int mt = blockIdx.x / ntn, nt = blockIdx.x % ntn;
  int lane = threadIdx.x;
  int rw = lane & 15, kq = lane >> 4;
  long arow = (long)batch * Mdim + (mt * 16 + rw);
  const u16* bp = Wt + (long)(nt * 16 + rw) * (4 * H) + kq * 8;
  f32x4 acc = {0.f, 0.f, 0.f, 0.f};
  for (int k = 0; k < 4 * H; k += 32) {
    int sec = k >> 7;
    int off = (k & 127) + kq * 8;
    long rb = arow * H + off;
    short8 av;
    if (sec == 0) {
      if (XF32) {
        const float* xp = (const float*)Xv + rb;
        float4 f0 = *(const float4*)(xp);
        float4 f1 = *(const float4*)(xp + 4);
        av[0] = (short)f2u(f0.x); av[1] = (short)f2u(f0.y);
        av[2] = (short)f2u(f0.z); av[3] = (short)f2u(f0.w);
        av[4] = (short)f2u(f1.x); av[5] = (short)f2u(f1.y);
        av[6] = (short)f2u(f1.z); av[7] = (short)f2u(f1.w);
      } else {
        av = *(const short8*)((const u16*)Xv + rb);
      }
    } else if (sec == 1) {
      av = *(const short8*)(P + rb);
    } else {
      float xf[8];
      if (XF32) {
        const float* xp = (const float*)Xv + rb;
        float4 f0 = *(const float4*)(xp);
        float4 f1 = *(const float4*)(xp + 4);
        xf[0] = f0.x; xf[1] = f0.y; xf[2] = f0.z; xf[3] = f0.w;
        xf[4] = f1.x; xf[5] = f1.y; xf[6] = f1.z; xf[7] = f1.w;
      } else {
        short8 xv = *(const short8*)((const u16*)Xv + rb);
        for (int i = 0; i < 8; i++) xf[i] = u2f((u16)xv[i]);
      }
      short8 pv = *(const short8*)((sec == 2 ? P : Qm) + rb);
      for (int i = 0; i < 8; i++) av[i] = (short)f2u(xf[i] * u2f((u16)pv[i]));
    }
    short8 bv = *(const short8*)(bp + k);
    acc = __builtin_amdgcn_mfma_f32_16x16x32_bf16(av, bv, acc, 0, 0, 0);
  }
  int gc = nt * 16 + rw;
  float cb = bias[gc];
  for (int i = 0; i < 4; i++) {
    int gr = mt * 16 + (kq * 4 + i);
    out[((long)batch * Mdim + gr) * H + gc] = acc[i] + cb;
  }
}

// ---------------- h = sum_r part; nr = sigmoid(h@Ww^T + rb); b_n = nr.wQ; c_n = nr.wC
__global__ void k_nr(const float* __restrict__ part, const float* __restrict__ Ww, const float* __restrict__ rb,
                     const float* __restrict__ wC, const float* __restrict__ wQ,
                     u16* __restrict__ nr, float* __restrict__ b_n, float* __restrict__ c_n) {
  int b = blockIdx.x / N, n = blockIdx.x % N;
  int t = threadIdx.x;  // 128
  __shared__ float hs[NB];
  if (t < NB) {
    float s = 0.f;
    for (int r = 0; r < R; r++) s += part[(((long)(b * R + r)) * N + n) * NB + t];
    hs[t] = s;
  }
  __syncthreads();
  float acc = rb[0];
  for (int k = 0; k < NB; k++) acc += hs[k] * Ww[t * NB + k];
  float s = 1.f / (1.f + expf(-acc));
  nr[((long)b * N + n) * H + t] = f2u(s);
  float bb = wredsum(s * wQ[t]), cc = wredsum(s * wC[t]);
  __shared__ float sb[2], sc[2];
  if ((t & 63) == 0) { sb[t >> 6] = bb; sc[t >> 6] = cc; }
  __syncthreads();
  if (t == 0) { b_n[(long)b * N + n] = sb[0] + sb[1]; c_n[(long)b * N + n] = sc[0] + sc[1]; }
}

// ---------------- fused row softmax: per (b,o) read Mm row once -> sq1, sc2
__global__ void k_soft_row2(const float* __restrict__ Mm, const float* __restrict__ b_n,
                            const float* __restrict__ c_n, const float* __restrict__ nmask,
                            u16* __restrict__ sq1, u16* __restrict__ sc2) {
  int b = blockIdx.x / Q, o = blockIdx.x % Q;
  int t = threadIdx.x;  // 256
  long ro = (long)b * Q + o;
  float v1[2], v2[2];
  for (int i = 0; i < 2; i++) {
    int n = t + 256 * i;
    float mv = Mm[ro * N + n];
    bool on = nmask[(long)b * N + n] > 0.f;
    v1[i] = on ? b_n[(long)b * N + n] + mv : -1e30f;
    v2[i] = on ? c_n[(long)b * N + n] + mv : -1e30f;
  }
  __shared__ float s1a[4], s2a[4];
  float m1 = wredmax(fmaxf(v1[0], v1[1]));
  float m2 = wredmax(fmaxf(v2[0], v2[1]));
  int wv = t >> 6;
  if ((t & 63) == 0) { s1a[wv] = m1; s2a[wv] = m2; }
  __syncthreads();
  m1 = fmaxf(fmaxf(s1a[0], s1a[1]), fmaxf(s1a[2], s1a[3]));
  m2 = fmaxf(fmaxf(s2a[0], s2a[1]), fmaxf(s2a[2], s2a[3]));
  __syncthreads();
  float e1[2], e2[2];
  e1[0] = expf(v1[0] - m1); e1[1] = expf(v1[1] - m1);
  e2[0] = expf(v2[0] - m2); e2[1] = expf(v2[1] - m2);
  float s1 = wredsum(e1[0] + e1[1]);
  float s2 = wredsum(e2[0] + e2[1]);
  if ((t & 63) == 0) { s1a[wv] = s1; s2a[wv] = s2; }
  __syncthreads();
  float r1 = 1.f / (s1a[0] + s1a[1] + s1a[2] + s1a[3]);
  float r2 = 1.f / (s2a[0] + s2a[1] + s2a[2] + s2a[3]);
  for (int i = 0; i < 2; i++) {
    int n = t + 256 * i;
    sq1[ro * N + n] = f2u(e1[i] * r1);
    sc2[ro * N + n] = f2u(e2[i] * r2);
  }
}

// ---------------- fused col softmax: per (b,n) read MmT row once -> sc1T, sq2
__global__ void k_soft_col2(const float* __restrict__ MmT, const float* __restrict__ a_o,
                            const float* __restrict__ d_o, const float* __restrict__ omask,
                            u16* __restrict__ sc1T, u16* __restrict__ sq2) {
  int b = blockIdx.x / N, n = blockIdx.x % N;
  int o = threadIdx.x;  // 256
  long rn = (long)b * N + n;
  float mv = MmT[rn * Q + o];
  bool on = omask[(long)b * Q + o] > 0.f;
  float v1 = on ? a_o[(long)b * Q + o] + mv : -1e30f;
  float v2 = on ? d_o[(long)b * Q + o] + mv : -1e30f;
  __shared__ float s1a[4], s2a[4];
  float m1 = wredmax(v1), m2 = wredmax(v2);
  int wv = o >> 6;
  if ((o & 63) == 0) { s1a[wv] = m1; s2a[wv] = m2; }
  __syncthreads();
  m1 = fmaxf(fmaxf(s1a[0], s1a[1]), fmaxf(s1a[2], s1a[3]));
  m2 = fmaxf(fmaxf(s2a[0], s2a[1]), fmaxf(s2a[2], s2a[3]));
  __syncthreads();
  float e1 = expf(v1 - m1), e2 = expf(v2 - m2);
  float s1 = wredsum(e1), s2 = wredsum(e2);
  if ((o & 63) == 0) { s1a[wv] = s1; s2a[wv] = s2; }
  __syncthreads();
  float r1 = 1.f / (s1a[0] + s1a[1] + s1a[2] + s1a[3]);
  float r2 = 1.f / (s2a[0] + s2a[1] + s2a[2] + s2a[3]);
  sc1T[rn * Q + o] = f2u(e1 * r1);
  sq2[rn * Q + o] = f2u(e2 * r2);
}

// ---------------- launch ----------------
extern "C" void kernel_launch(void* const* d_in, const int* in_sizes, int n_in,
                              void* d_out, int out_size, void* d_ws, size_t ws_size,
                              hipStream_t stream) {
  const float* nf    = (const float*)d_in[0];
  const float* rf    = (const float*)d_in[1];
  const float* adj   = (const float*)d_in[2];
  const float* obs   = (const float*)d_in[3];
  const float* nmask = (const float*)d_in[4];
  const float* omask = (const float*)d_in[5];
  const float* Wb    = (const float*)d_in[6];
  const float* Ww    = (const float*)d_in[7];
  const float* rb    = (const float*)d_in[8];
  const float* wC    = (const float*)d_in[9];
  const float* wQ    = (const float*)d_in[10];
  const float* wCQ   = (const float*)d_in[11];
  // d_in[12] = cq_bias: uniform shift along both softmax axes -> cancels, unused
  const float* linW  = (const float*)d_in[13];
  const float* linb  = (const float*)d_in[14];
  float* outp = (float*)d_out;

  char* w = (char*)d_ws;
  auto alloc = [&](size_t bytes) { char* p = w; w += (bytes + 255) & ~(size_t)255; return p; };
  u16*   linWb = (u16*)  alloc((size_t)H * 4 * H * 2);
  u16*   WbB   = (u16*)  alloc((size_t)R * NB * 128 * 2);
  float* vv    = (float*)alloc((size_t)B * R * NB * 4);
  u16*   obsW  = (u16*)  alloc((size_t)B * Q * H * 2);
  u16*   obsT  = (u16*)  alloc((size_t)B * H * Q * 2);
  float* a_o   = (float*)alloc((size_t)B * Q * 4);
  float* d_o   = (float*)alloc((size_t)B * Q * 4);
  float* b_n   = (float*)alloc((size_t)B * N * 4);
  float* c_n   = (float*)alloc((size_t)B * N * 4);
  u16*   nr    = (u16*)  alloc((size_t)B * N * H * 2);
  u16*   nrT   = (u16*)  alloc((size_t)B * H * N * 2);
  u16*   tT    = (u16*)  alloc((size_t)B * R * NB * N * 2);
  float* part  = (float*)alloc((size_t)B * R * N * NB * 4);
  float* Mm    = (float*)alloc((size_t)B * Q * N * 4);
  float* MmT   = (float*)alloc((size_t)B * N * Q * 4);
  u16*   sq1   = (u16*)  alloc((size_t)B * Q * N * 2);
  u16*   sc2   = (u16*)  alloc((size_t)B * Q * N * 2);
  u16*   sc1T  = (u16*)  alloc((size_t)B * N * Q * 2);
  u16*   sq2   = (u16*)  alloc((size_t)B * N * Q * 2);
  u16*   P1    = (u16*)  alloc((size_t)B * Q * H * 2);
  u16*   T1T   = (u16*)  alloc((size_t)B * H * N * 2);
  u16*   Qm1   = (u16*)  alloc((size_t)B * Q * H * 2);
  u16*   P2    = (u16*)  alloc((size_t)B * N * H * 2);
  u16*   T2T   = (u16*)  alloc((size_t)B * H * Q * 2);
  u16*   Qm2   = (u16*)  alloc((size_t)B * N * H * 2);

  // ---- prep ----
  k_prep_w<<<144, 256, 0, stream>>>(linW, linWb, Wb, WbB);
  k_v<<<B * R, 128, 0, stream>>>(rf, Wb, vv);
  k_obs_prep<<<B * Q, 128, 0, stream>>>(obs, wC, wQ, wCQ, obsW, a_o, d_o);
  k_transpose<true><<<dim3(H / 32, Q / 32, B), dim3(32, 8), 0, stream>>>(obs, obsT, Q, H);

  // ---- RGCN ----
  // tT[b,r](16 x N) = WbB[r](16 x 128) @ nf[b]^T + v[b,r]  (nf f32 in-register cvt)
  gemm_bt<false, true, 0, false, 2, true, 2><<<dim3(N / 16, B * R), 64, 0, stream>>>(
      WbB, nf, tT, nullptr, vv, NB, N, H, (long)NB * 128, (long)N * H, (long)NB * N, 0);
  // part[b,r](N x 16) = adj[b,r] @ tT[b,r]^T   (adj f32 in-register cvt, deep unroll)
  gemm_bt<true, false, 1, false, 0, false, 4><<<dim3(N / 16, B * R), 64, 0, stream>>>(
      adj, tT, part, nullptr, nullptr, N, NB, N, (long)N * N, (long)NB * N, (long)N * NB, 0);
  k_nr<<<B * N, 128, 0, stream>>>(part, Ww, rb, wC, wQ, nr, b_n, c_n);
  k_transpose<false><<<dim3(H / 32, N / 32, B), dim3(32, 8), 0, stream>>>(nr, nrT, N, H);

  // ---- bilinear core M = (obs .* w_CQ) @ nr^T, dual f32 out (Mm + MmT) ----
  gemm_bt<false, false, 2, false, 0, false, 2><<<dim3((Q / 16) * (N / 16), B), 64, 0, stream>>>(
      obsW, nr, Mm, MmT, nullptr, Q, N, H, (long)Q * H, (long)N * H, (long)Q * N, (long)N * Q);

  // ---- fused masked softmaxes ----
  k_soft_row2<<<B * Q, 256, 0, stream>>>(Mm, b_n, c_n, nmask, sq1, sc2);
  k_soft_col2<<<B * N, 256, 0, stream>>>(MmT, a_o, d_o, omask, sc1T, sq2);

  // ---- 4 independent attention GEMMs in one launch ----
  GPar pP1  = {sq1,  nrT,  P1,  Q, N, (long)Q * N, (long)H * N, (long)Q * H, 0};
  GPar pT2T = {sc2,  nrT,  T2T, Q, N, (long)Q * N, (long)H * N, (long)H * Q, 1};
  GPar pT1T = {sc1T, obsT, T1T, N, Q, (long)N * Q, (long)H * Q, (long)H * N, 1};
  GPar pP2  = {sq2,  obsT, P2,  N, Q, (long)N * Q, (long)H * Q, (long)N * H, 0};
  gemm_quad<<<dim3((N / 16) * (H / 16), B, 4), 64, 0, stream>>>(pP1, pT2T, pT1T, pP2, H);
  // ---- Qm pair ----
  GPar pQm1 = {sq1, T1T, Qm1, Q, N, (long)Q * N, (long)H * N, (long)Q * H, 0};
  GPar pQm2 = {sq2, T2T, Qm2, N, Q, (long)N * Q, (long)H * Q, (long)N * H, 0};
  gemm_quad<<<dim3((N / 16) * (H / 16), B, 2), 64, 0, stream>>>(pQm1, pQm2, pQm1, pQm2, H);

  // ---- fused concat + output linear (f32 out) ----
  gemm_cat<true ><<<dim3((Q / 16) * (H / 16), B), 64, 0, stream>>>(
      obs, P1, Qm1, linWb, linb, outp, Q);
  gemm_cat<false><<<dim3((N / 16) * (H / 16), B), 64, 0, stream>>>(
      nr, P2, Qm2, linWb, linb, outp + (long)B * Q * H, N);

  (void)in_sizes; (void)n_in; (void)out_size; (void)ws_size;
}

// Round 5
// 331.943 us; speedup vs baseline: 1.6787x; 1.0772x over previous
//
#include <hip/hip_runtime.h>
#include <hip/hip_bf16.h>
#include <stdint.h>

typedef unsigned short u16;
typedef __attribute__((ext_vector_type(8))) short short8;
typedef __attribute__((ext_vector_type(4))) float f32x4;

#define DEVI static __device__ __forceinline__

constexpr int B = 32, R = 10, N = 512, H = 128, Q = 256, NB = 16;
constexpr int KWB = 2560;  // (DN+DR)*R

DEVI u16 f2u(float f) { return __builtin_bit_cast(unsigned short, __float2bfloat16(f)); }
DEVI float u2f(u16 u) { union { uint32_t i; float f; } c; c.i = ((uint32_t)u) << 16; return c.f; }

DEVI float wredmax(float v) { for (int o = 32; o; o >>= 1) v = fmaxf(v, __shfl_xor(v, o)); return v; }
DEVI float wredsum(float v) { for (int o = 32; o; o >>= 1) v += __shfl_xor(v, o); return v; }

// ---------------- merged prep: linWb | WbB | WwB(pad32) | vv | obs_prep ----------------
__global__ __launch_bounds__(256) void k_prep(
    const float* __restrict__ linW, u16* __restrict__ linWb,
    const float* __restrict__ Wb, u16* __restrict__ WbB,
    const float* __restrict__ Ww, u16* __restrict__ WwB,
    const float* __restrict__ rf, float* __restrict__ vv,
    const float* __restrict__ obs, const float* __restrict__ wC,
    const float* __restrict__ wQ, const float* __restrict__ wCQ,
    u16* __restrict__ obsW, float* __restrict__ a_o, float* __restrict__ d_o) {
  int bid = blockIdx.x, t = threadIdx.x;
  if (bid < 64) {                       // linW f32 -> bf16 (v4)
    int i = bid * 256 + t;
    float4 f = ((const float4*)linW)[i];
    ushort4 o;
    o.x = f2u(f.x); o.y = f2u(f.y); o.z = f2u(f.z); o.w = f2u(f.w);
    ((ushort4*)linWb)[i] = o;
  } else if (bid < 144) {               // WbB[r][k][d] = bf16(Wb[k][r*256+d]), d<128
    int rk = (bid - 64) * 2 + (t >> 7);
    int d = t & 127;
    int r = rk / NB, k = rk % NB;
    WbB[(long)rk * 128 + d] = f2u(Wb[(long)k * KWB + r * 256 + d]);
  } else if (bid < 160) {               // WwB[h][kb] padded to 32
    int idx = (bid - 144) * 256 + t;    // 4096
    int h = idx >> 5, kb = idx & 31;
    WwB[idx] = (kb < NB) ? f2u(Ww[h * NB + kb]) : (u16)0;
  } else if (bid < 1440) {              // vv: wave per (b,r,k)
    int w = t >> 6, lane = t & 63;
    int gid = (bid - 160) * 4 + w;      // 0..5119
    int b = gid / (R * NB), rk = gid % (R * NB), r = rk / NB, k = rk % NB;
    float s = 0.f;
    for (int dd = 0; dd < 2; ++dd) {
      int d = lane + dd * 64;
      s += rf[((long)b * R + r) * H + d] * Wb[(long)k * KWB + r * 256 + 128 + d];
    }
    s = wredsum(s);
    if (lane == 0) vv[((long)b * R + r) * NB + k] = s;
  } else {                              // obs prep: 2 rows per block
    int row = (bid - 1440) * 2 + (t >> 7);  // b*Q + o
    int tt = t & 127;
    float x = obs[(long)row * H + tt];
    obsW[(long)row * H + tt] = f2u(x * wCQ[tt]);
    float aa = wredsum(x * wC[tt]);
    float dd2 = wredsum(x * wQ[tt]);
    __shared__ float sa[4], sd[4];
    int wv = t >> 6;
    if ((t & 63) == 0) { sa[wv] = aa; sd[wv] = dd2; }
    __syncthreads();
    if ((t & 127) == 0) {
      int h = t >> 7;
      a_o[row] = sa[h * 2] + sa[h * 2 + 1];
      d_o[row] = sd[h * 2] + sd[h * 2 + 1];
    }
  }
}

// ---------------- tiled transpose: in[batch][Rr][Cc] -> out[batch][Cc][Rr] (bf16 out)
template <bool INF32>
__global__ void k_transpose(const void* __restrict__ in, u16* __restrict__ out, int Rr, int Cc) {
  __shared__ u16 tile[32][33];
  int batch = blockIdx.z;
  int c0 = blockIdx.x * 32, r0 = blockIdx.y * 32;
  int tx = threadIdx.x, ty = threadIdx.y;  // 32 x 8
  for (int i = 0; i < 4; i++) {
    int r = r0 + ty + i * 8, c = c0 + tx;
    if (INF32) tile[ty + i * 8][tx] = f2u(((const float*)in)[((long)batch * Rr + r) * Cc + c]);
    else       tile[ty + i * 8][tx] = ((const u16*)in)[((long)batch * Rr + r) * Cc + c];
  }
  __syncthreads();
  for (int i = 0; i < 4; i++) {
    int c = c0 + ty + i * 8, r = r0 + tx;
    out[((long)batch * Cc + c) * Rr + r] = tile[tx][ty + i * 8];
  }
}

// ---------------- generic batched MFMA GEMM (unchanged core)
template <bool AF32, bool BF32, int CMODE, bool TRANSC, int BMODE, bool RGRID, int UNROLL>
__global__ __launch_bounds__(64) void gemm_bt(const void* __restrict__ Av, const void* __restrict__ Btv,
                                              void* __restrict__ Cp, float* __restrict__ C2,
                                              const float* __restrict__ bias,
                                              int Mdim, int Ndim, int Kdim,
                                              long sA, long sBt, long sC, long sC2) {
  int batch = blockIdx.y;
  int ab = batch, bb = batch;
  if (RGRID) { ab = batch % R; bb = batch / R; }
  int ntn = Ndim >> 4;
  int mt = blockIdx.x / ntn, nt = blockIdx.x % ntn;
  int lane = threadIdx.x;
  int rw = lane & 15, kq = lane >> 4;
  long aoff = (long)ab * sA + (long)(mt * 16 + rw) * Kdim + kq * 8;
  long boff = (long)bb * sBt + (long)(nt * 16 + rw) * Kdim + kq * 8;
  f32x4 acc = {0.f, 0.f, 0.f, 0.f};
#pragma unroll UNROLL
  for (int k = 0; k < Kdim; k += 32) {
    short8 av, bv;
    if (AF32) {
      const float* ap = (const float*)Av + aoff + k;
      float4 f0 = *(const float4*)(ap);
      float4 f1 = *(const float4*)(ap + 4);
      av[0] = (short)f2u(f0.x); av[1] = (short)f2u(f0.y);
      av[2] = (short)f2u(f0.z); av[3] = (short)f2u(f0.w);
      av[4] = (short)f2u(f1.x); av[5] = (short)f2u(f1.y);
      av[6] = (short)f2u(f1.z); av[7] = (short)f2u(f1.w);
    } else {
      av = *(const short8*)((const u16*)Av + aoff + k);
    }
    if (BF32) {
      const float* bp = (const float*)Btv + boff + k;
      float4 f0 = *(const float4*)(bp);
      float4 f1 = *(const float4*)(bp + 4);
      bv[0] = (short)f2u(f0.x); bv[1] = (short)f2u(f0.y);
      bv[2] = (short)f2u(f0.z); bv[3] = (short)f2u(f0.w);
      bv[4] = (short)f2u(f1.x); bv[5] = (short)f2u(f1.y);
      bv[6] = (short)f2u(f1.z); bv[7] = (short)f2u(f1.w);
    } else {
      bv = *(const short8*)((const u16*)Btv + boff + k);
    }
    acc = __builtin_amdgcn_mfma_f32_16x16x32_bf16(av, bv, acc, 0, 0, 0);
  }
  int gc = nt * 16 + rw;
  float cb = (BMODE == 1) ? bias[gc] : 0.f;
  for (int i = 0; i < 4; i++) {
    int gr = mt * 16 + (kq * 4 + i);
    float val = acc[i] + cb;
    if (BMODE == 2) val += bias[(long)batch * NB + gr];
    if (CMODE == 2) {
      ((float*)Cp)[(long)batch * sC + (long)gr * Ndim + gc] = val;
      C2[(long)batch * sC2 + (long)gc * Mdim + gr] = val;
    } else {
      long idx = TRANSC ? ((long)gc * Mdim + gr) : ((long)gr * Ndim + gc);
      if (CMODE == 1) ((float*)Cp)[(long)batch * sC + idx] = val;
      else            ((u16*)Cp)[(long)batch * sC + idx] = f2u(val);
    }
  }
}

// ---------------- RGCN mega-kernel: h = sum_r adj[b,r] @ t[b,r]; nr = sigmoid(h@Ww^T+rb);
// also b_n = nr.wQ, c_n = nr.wC.  grid (N/16, B), 256 threads (4 waves).
__global__ __launch_bounds__(256) void k_rgcn(
    const float* __restrict__ adj, const u16* __restrict__ tT,
    const u16* __restrict__ WwB, const float* __restrict__ rb,
    const float* __restrict__ wC, const float* __restrict__ wQ,
    u16* __restrict__ nr, float* __restrict__ b_n, float* __restrict__ c_n) {
  int ntile = blockIdx.x, b = blockIdx.y;
  int n0 = ntile * 16;
  int tid = threadIdx.x;
  int w = tid >> 6, lane = tid & 63;
  int rw = lane & 15, kq = lane >> 4;
  __shared__ float hred[4][16][17];
  __shared__ __align__(16) u16 hbf[16][32];
  __shared__ float bpc[4][16][2];
  float rbv = rb[0];

  // phase 1: flattened K (r*16 + kit), wave w takes every 4th chunk
  f32x4 acc = {0.f, 0.f, 0.f, 0.f};
#pragma unroll 4
  for (int j = 0; j < 40; ++j) {
    int kkk = w + 4 * j;
    int r = kkk >> 4, k = (kkk & 15) * 32;
    const float* ap = adj + (((long)(b * R + r) * N) + n0 + rw) * N + k + kq * 8;
    float4 f0 = *(const float4*)ap;
    float4 f1 = *(const float4*)(ap + 4);
    short8 av;
    av[0] = (short)f2u(f0.x); av[1] = (short)f2u(f0.y);
    av[2] = (short)f2u(f0.z); av[3] = (short)f2u(f0.w);
    av[4] = (short)f2u(f1.x); av[5] = (short)f2u(f1.y);
    av[6] = (short)f2u(f1.z); av[7] = (short)f2u(f1.w);
    short8 bv = *(const short8*)(tT + ((long)(b * R + r) * NB + rw) * N + k + kq * 8);
    acc = __builtin_amdgcn_mfma_f32_16x16x32_bf16(av, bv, acc, 0, 0, 0);
  }
  for (int i = 0; i < 4; i++) hred[w][kq * 4 + i][rw] = acc[i];
  __syncthreads();
  {  // cross-wave reduce, convert to bf16, zero-pad K to 32
    int n = tid >> 4, kb = tid & 15;
    float s = hred[0][n][kb] + hred[1][n][kb] + hred[2][n][kb] + hred[3][n][kb];
    hbf[n][kb] = f2u(s);
    hbf[n][kb + 16] = 0;
  }
  __syncthreads();

  // phase 2: wave w computes h-col tiles nt = 2w, 2w+1
  float bsum[4] = {0.f, 0.f, 0.f, 0.f}, csum[4] = {0.f, 0.f, 0.f, 0.f};
  for (int half = 0; half < 2; ++half) {
    int nt = w * 2 + half;
    short8 av = *(const short8*)&hbf[rw][kq * 8];
    short8 bv = *(const short8*)(WwB + (long)(nt * 16 + rw) * 32 + kq * 8);
    f32x4 a2 = {0.f, 0.f, 0.f, 0.f};
    a2 = __builtin_amdgcn_mfma_f32_16x16x32_bf16(av, bv, a2, 0, 0, 0);
    int h = nt * 16 + rw;
    float wq = wQ[h], wc = wC[h];
    for (int i = 0; i < 4; i++) {
      float s = 1.f / (1.f + expf(-(a2[i] + rbv)));
      int n = n0 + kq * 4 + i;
      nr[((long)b * N + n) * H + h] = f2u(s);
      bsum[i] += s * wq;
      csum[i] += s * wc;
    }
  }
  for (int i = 0; i < 4; i++) {
    for (int o = 8; o; o >>= 1) { bsum[i] += __shfl_xor(bsum[i], o); csum[i] += __shfl_xor(csum[i], o); }
  }
  if (rw == 0)
    for (int i = 0; i < 4; i++) { bpc[w][kq * 4 + i][0] = bsum[i]; bpc[w][kq * 4 + i][1] = csum[i]; }
  __syncthreads();
  if (tid < 32) {
    int ns = tid & 15, which = tid >> 4;
    float s = bpc[0][ns][which] + bpc[1][ns][which] + bpc[2][ns][which] + bpc[3][ns][which];
    (which ? c_n : b_n)[(long)b * N + n0 + ns] = s;
  }
}

// ---------------- z-multiplexed bf16 GEMMs
struct GPar {
  const u16* A; const u16* Bt; u16* C;
  int Mdim; int Kdim; long sA, sBt, sC; int tc;
};
__global__ __launch_bounds__(64) void gemm_quad(GPar p0, GPar p1, GPar p2, GPar p3, int Ndim) {
  int z = blockIdx.z;
  GPar p = (z == 0) ? p0 : (z == 1) ? p1 : (z == 2) ? p2 : p3;
  int batch = blockIdx.y;
  int ntn = Ndim >> 4;
  int mt = blockIdx.x / ntn, nt = blockIdx.x % ntn;
  if (mt * 16 >= p.Mdim) return;
  int lane = threadIdx.x;
  int rw = lane & 15, kq = lane >> 4;
  const u16* ap = p.A + (long)batch * p.sA + (long)(mt * 16 + rw) * p.Kdim + kq * 8;
  const u16* bp = p.Bt + (long)batch * p.sBt + (long)(nt * 16 + rw) * p.Kdim + kq * 8;
  f32x4 acc = {0.f, 0.f, 0.f, 0.f};
#pragma unroll 2
  for (int k = 0; k < p.Kdim; k += 32) {
    short8 av = *(const short8*)(ap + k);
    short8 bv = *(const short8*)(bp + k);
    acc = __builtin_amdgcn_mfma_f32_16x16x32_bf16(av, bv, acc, 0, 0, 0);
  }
  int gc = nt * 16 + rw;
  for (int i = 0; i < 4; i++) {
    int gr = mt * 16 + (kq * 4 + i);
    long idx = p.tc ? ((long)gc * p.Mdim + gr) : ((long)gr * Ndim + gc);
    p.C[(long)batch * p.sC + idx] = f2u(acc[i]);
  }
}

// ---------------- fused concat+output GEMM
template <bool XF32>
__global__ __launch_bounds__(64) void gemm_cat(const void* __restrict__ Xv, const u16* __restrict__ P,
                                               const u16* __restrict__ Qm, const u16* __restrict__ Wt,
                                               const float* __restrict__ bias, float* __restrict__ out,
                                               int Mdim) {
  int batch = blockIdx.y;
  int ntn = H >> 4;
  int mt = blockIdx.x / ntn, nt = blockIdx.x % ntn;
  int lane = threadIdx.x;
  int rw = lane & 15, kq = lane >> 4;
  long arow = (long)batch * Mdim + (mt * 16 + rw);
  const u16* bp = Wt + (long)(nt * 16 + rw) * (4 * H) + kq * 8;
  f32x4 acc = {0.f, 0.f, 0.f, 0.f};
  for (int k = 0; k < 4 * H; k += 32) {
    int sec = k >> 7;
    int off = (k & 127) + kq * 8;
    long rb2 = arow * H + off;
    short8 av;
    if (sec == 0) {
      if (XF32) {
        const float* xp = (const float*)Xv + rb2;
        float4 f0 = *(const float4*)(xp);
        float4 f1 = *(const float4*)(xp + 4);
        av[0] = (short)f2u(f0.x); av[1] = (short)f2u(f0.y);
        av[2] = (short)f2u(f0.z); av[3] = (short)f2u(f0.w);
        av[4] = (short)f2u(f1.x); av[5] = (short)f2u(f1.y);
        av[6] = (short)f2u(f1.z); av[7] = (short)f2u(f1.w);
      } else {
        av = *(const short8*)((const u16*)Xv + rb2);
      }
    } else if (sec == 1) {
      av = *(const short8*)(P + rb2);
    } else {
      float xf[8];
      if (XF32) {
        const float* xp = (const float*)Xv + rb2;
        float4 f0 = *(const float4*)(xp);
        float4 f1 = *(const float4*)(xp + 4);
        xf[0] = f0.x; xf[1] = f0.y; xf[2] = f0.z; xf[3] = f0.w;
        xf[4] = f1.x; xf[5] = f1.y; xf[6] = f1.z; xf[7] = f1.w;
      } else {
        short8 xv = *(const short8*)((const u16*)Xv + rb2);
        for (int i = 0; i < 8; i++) xf[i] = u2f((u16)xv[i]);
      }
      short8 pv = *(const short8*)((sec == 2 ? P : Qm) + rb2);
      for (int i = 0; i < 8; i++) av[i] = (short)f2u(xf[i] * u2f((u16)pv[i]));
    }
    short8 bv = *(const short8*)(bp + k);
    acc = __builtin_amdgcn_mfma_f32_16x16x32_bf16(av, bv, acc, 0, 0, 0);
  }
  int gc = nt * 16 + rw;
  float cb = bias[gc];
  for (int i = 0; i < 4; i++) {
    int gr = mt * 16 + (kq * 4 + i);
    out[((long)batch * Mdim + gr) * H + gc] = acc[i] + cb;
  }
}

// ---------------- combined softmax: blocks [0, B*Q) row path; [B*Q, B*Q+B*N) col path
__global__ __launch_bounds__(256) void k_soft_both(
    const float* __restrict__ Mm, const float* __restrict__ MmT,
    const float* __restrict__ b_n, const float* __restrict__ c_n,
    const float* __restrict__ a_o, const float* __restrict__ d_o,
    const float* __restrict__ nmask, const float* __restrict__ omask,
    u16* __restrict__ sq1, u16* __restrict__ sc2,
    u16* __restrict__ sc1T, u16* __restrict__ sq2) {
  int bid = blockIdx.x;
  __shared__ float s1a[4], s2a[4];
  if (bid < B * Q) {
    int b = bid / Q;
    int t = threadIdx.x;
    long ro = bid;
    float v1[2], v2[2];
    for (int i = 0; i < 2; i++) {
      int n = t + 256 * i;
      float mv = Mm[ro * N + n];
      bool on = nmask[(long)b * N + n] > 0.f;
      v1[i] = on ? b_n[(long)b * N + n] + mv : -1e30f;
      v2[i] = on ? c_n[(long)b * N + n] + mv : -1e30f;
    }
    float m1 = wredmax(fmaxf(v1[0], v1[1]));
    float m2 = wredmax(fmaxf(v2[0], v2[1]));
    int wv = t >> 6;
    if ((t & 63) == 0) { s1a[wv] = m1; s2a[wv] = m2; }
    __syncthreads();
    m1 = fmaxf(fmaxf(s1a[0], s1a[1]), fmaxf(s1a[2], s1a[3]));
    m2 = fmaxf(fmaxf(s2a[0], s2a[1]), fmaxf(s2a[2], s2a[3]));
    __syncthreads();
    float e1[2], e2[2];
    e1[0] = expf(v1[0] - m1); e1[1] = expf(v1[1] - m1);
    e2[0] = expf(v2[0] - m2); e2[1] = expf(v2[1] - m2);
    float s1 = wredsum(e1[0] + e1[1]);
    float s2 = wredsum(e2[0] + e2[1]);
    if ((t & 63) == 0) { s1a[wv] = s1; s2a[wv] = s2; }
    __syncthreads();
    float r1 = 1.f / (s1a[0] + s1a[1] + s1a[2] + s1a[3]);
    float r2 = 1.f / (s2a[0] + s2a[1] + s2a[2] + s2a[3]);
    for (int i = 0; i < 2; i++) {
      int n = t + 256 * i;
      sq1[ro * N + n] = f2u(e1[i] * r1);
      sc2[ro * N + n] = f2u(e2[i] * r2);
    }
  } else {
    int id = bid - B * Q;
    int b = id / N;
    int o = threadIdx.x;
    long rn = id;
    float mv = MmT[rn * Q + o];
    bool on = omask[(long)b * Q + o] > 0.f;
    float v1 = on ? a_o[(long)b * Q + o] + mv : -1e30f;
    float v2 = on ? d_o[(long)b * Q + o] + mv : -1e30f;
    float m1 = wredmax(v1), m2 = wredmax(v2);
    int wv = o >> 6;
    if ((o & 63) == 0) { s1a[wv] = m1; s2a[wv] = m2; }
    __syncthreads();
    m1 = fmaxf(fmaxf(s1a[0], s1a[1]), fmaxf(s1a[2], s1a[3]));
    m2 = fmaxf(fmaxf(s2a[0], s2a[1]), fmaxf(s2a[2], s2a[3]));
    __syncthreads();
    float e1 = expf(v1 - m1), e2 = expf(v2 - m2);
    float s1 = wredsum(e1), s2 = wredsum(e2);
    if ((o & 63) == 0) { s1a[wv] = s1; s2a[wv] = s2; }
    __syncthreads();
    float r1 = 1.f / (s1a[0] + s1a[1] + s1a[2] + s1a[3]);
    float r2 = 1.f / (s2a[0] + s2a[1] + s2a[2] + s2a[3]);
    sc1T[rn * Q + o] = f2u(e1 * r1);
    sq2[rn * Q + o] = f2u(e2 * r2);
  }
}

// ---------------- launch ----------------
extern "C" void kernel_launch(void* const* d_in, const int* in_sizes, int n_in,
                              void* d_out, int out_size, void* d_ws, size_t ws_size,
                              hipStream_t stream) {
  const float* nf    = (const float*)d_in[0];
  const float* rf    = (const float*)d_in[1];
  const float* adj   = (const float*)d_in[2];
  const float* obs   = (const float*)d_in[3];
  const float* nmask = (const float*)d_in[4];
  const float* omask = (const float*)d_in[5];
  const float* Wb    = (const float*)d_in[6];
  const float* Ww    = (const float*)d_in[7];
  const float* rb    = (const float*)d_in[8];
  const float* wC    = (const float*)d_in[9];
  const float* wQ    = (const float*)d_in[10];
  const float* wCQ   = (const float*)d_in[11];
  // d_in[12] = cq_bias: uniform shift along both softmax axes -> cancels, unused
  const float* linW  = (const float*)d_in[13];
  const float* linb  = (const float*)d_in[14];
  float* outp = (float*)d_out;

  char* w = (char*)d_ws;
  auto alloc = [&](size_t bytes) { char* p = w; w += (bytes + 255) & ~(size_t)255; return p; };
  u16*   linWb = (u16*)  alloc((size_t)H * 4 * H * 2);
  u16*   WbB   = (u16*)  alloc((size_t)R * NB * 128 * 2);
  u16*   WwB   = (u16*)  alloc((size_t)H * 32 * 2);
  float* vv    = (float*)alloc((size_t)B * R * NB * 4);
  u16*   obsW  = (u16*)  alloc((size_t)B * Q * H * 2);
  u16*   obsT  = (u16*)  alloc((size_t)B * H * Q * 2);
  float* a_o   = (float*)alloc((size_t)B * Q * 4);
  float* d_o   = (float*)alloc((size_t)B * Q * 4);
  float* b_n   = (float*)alloc((size_t)B * N * 4);
  float* c_n   = (float*)alloc((size_t)B * N * 4);
  u16*   nr    = (u16*)  alloc((size_t)B * N * H * 2);
  u16*   nrT   = (u16*)  alloc((size_t)B * H * N * 2);
  u16*   tT    = (u16*)  alloc((size_t)B * R * NB * N * 2);
  float* Mm    = (float*)alloc((size_t)B * Q * N * 4);
  float* MmT   = (float*)alloc((size_t)B * N * Q * 4);
  u16*   sq1   = (u16*)  alloc((size_t)B * Q * N * 2);
  u16*   sc2   = (u16*)  alloc((size_t)B * Q * N * 2);
  u16*   sc1T  = (u16*)  alloc((size_t)B * N * Q * 2);
  u16*   sq2   = (u16*)  alloc((size_t)B * N * Q * 2);
  u16*   P1    = (u16*)  alloc((size_t)B * Q * H * 2);
  u16*   T1T   = (u16*)  alloc((size_t)B * H * N * 2);
  u16*   Qm1   = (u16*)  alloc((size_t)B * Q * H * 2);
  u16*   P2    = (u16*)  alloc((size_t)B * N * H * 2);
  u16*   T2T   = (u16*)  alloc((size_t)B * H * Q * 2);
  u16*   Qm2   = (u16*)  alloc((size_t)B * N * H * 2);

  // ---- prep (one launch) + obs transpose ----
  k_prep<<<1440 + B * Q / 2, 256, 0, stream>>>(linW, linWb, Wb, WbB, Ww, WwB,
                                               rf, vv, obs, wC, wQ, wCQ, obsW, a_o, d_o);
  k_transpose<true><<<dim3(H / 32, Q / 32, B), dim3(32, 8), 0, stream>>>(obs, obsT, Q, H);

  // ---- RGCN ----
  // tT[b,r](16 x N) = WbB[r](16 x 128) @ nf[b]^T + v[b,r]
  gemm_bt<false, true, 0, false, 2, true, 2><<<dim3(N / 16, B * R), 64, 0, stream>>>(
      WbB, nf, tT, nullptr, vv, NB, N, H, (long)NB * 128, (long)N * H, (long)NB * N, 0);
  // mega: h = sum_r adj@t ; nr = sigmoid(h@Ww^T+rb); b_n; c_n
  k_rgcn<<<dim3(N / 16, B), 256, 0, stream>>>(adj, tT, WwB, rb, wC, wQ, nr, b_n, c_n);
  k_transpose<false><<<dim3(H / 32, N / 32, B), dim3(32, 8), 0, stream>>>(nr, nrT, N, H);

  // ---- bilinear core M = (obs .* w_CQ) @ nr^T, dual f32 out (Mm + MmT) ----
  gemm_bt<false, false, 2, false, 0, false, 2><<<dim3((Q / 16) * (N / 16), B), 64, 0, stream>>>(
      obsW, nr, Mm, MmT, nullptr, Q, N, H, (long)Q * H, (long)N * H, (long)Q * N, (long)N * Q);

  // ---- fused masked softmaxes (one launch) ----
  k_soft_both<<<B * Q + B * N, 256, 0, stream>>>(Mm, MmT, b_n, c_n, a_o, d_o, nmask, omask,
                                                 sq1, sc2, sc1T, sq2);

  // ---- 4 independent attention GEMMs in one launch ----
  GPar pP1  = {sq1,  nrT,  P1,  Q, N, (long)Q * N, (long)H * N, (long)Q * H, 0};
  GPar pT2T = {sc2,  nrT,  T2T, Q, N, (long)Q * N, (long)H * N, (long)H * Q, 1};
  GPar pT1T = {sc1T, obsT, T1T, N, Q, (long)N * Q, (long)H * Q, (long)H * N, 1};
  GPar pP2  = {sq2,  obsT, P2,  N, Q, (long)N * Q, (long)H * Q, (long)N * H, 0};
  gemm_quad<<<dim3((N / 16) * (H / 16), B, 4), 64, 0, stream>>>(pP1, pT2T, pT1T, pP2, H);
  GPar pQm1 = {sq1, T1T, Qm1, Q, N, (long)Q * N, (long)H * N, (long)Q * H, 0};
  GPar pQm2 = {sq2, T2T, Qm2, N, Q, (long)N * Q, (long)H * Q, (long)N * H, 0};
  gemm_quad<<<dim3((N / 16) * (H / 16), B, 2), 64, 0, stream>>>(pQm1, pQm2, pQm1, pQm2, H);

  // ---- fused concat + output linear (f32 out) ----
  gemm_cat<true ><<<dim3((Q / 16) * (H / 16), B), 64, 0, stream>>>(
      obs, P1, Qm1, linWb, linb, outp, Q);
  gemm_cat<false><<<dim3((N / 16) * (H / 16), B), 64, 0, stream>>>(
      nr, P2, Qm2, linWb, linb, outp + (long)B * Q * H, N);

  (void)in_sizes; (void)n_in; (void)out_size; (void)ws_size;
}

// Round 6
// 297.580 us; speedup vs baseline: 1.8725x; 1.1155x over previous
//
#include <hip/hip_runtime.h>
#include <hip/hip_bf16.h>
#include <stdint.h>

typedef unsigned short u16;
typedef __attribute__((ext_vector_type(8))) short short8;
typedef __attribute__((ext_vector_type(4))) float f32x4;

#define DEVI static __device__ __forceinline__

constexpr int B = 32, R = 10, N = 512, H = 128, Q = 256, NB = 16;
constexpr int KWB = 2560;  // (DN+DR)*R

DEVI u16 f2u(float f) { return __builtin_bit_cast(unsigned short, __float2bfloat16(f)); }
DEVI float u2f(u16 u) { union { uint32_t i; float f; } c; c.i = ((uint32_t)u) << 16; return c.f; }

DEVI float wredmax(float v) { for (int o = 32; o; o >>= 1) v = fmaxf(v, __shfl_xor(v, o)); return v; }
DEVI float wredsum(float v) { for (int o = 32; o; o >>= 1) v += __shfl_xor(v, o); return v; }

DEVI short8 cvt8(const float* p) {
  float4 f0 = *(const float4*)p;
  float4 f1 = *(const float4*)(p + 4);
  short8 v;
  v[0] = (short)f2u(f0.x); v[1] = (short)f2u(f0.y);
  v[2] = (short)f2u(f0.z); v[3] = (short)f2u(f0.w);
  v[4] = (short)f2u(f1.x); v[5] = (short)f2u(f1.y);
  v[6] = (short)f2u(f1.z); v[7] = (short)f2u(f1.w);
  return v;
}

// ---------------- merged prep: linWb | WbB | WwB(pad32) | vv | obs_prep | obsT ----------------
__global__ __launch_bounds__(256) void k_prep(
    const float* __restrict__ linW, u16* __restrict__ linWb,
    const float* __restrict__ Wb, u16* __restrict__ WbB,
    const float* __restrict__ Ww, u16* __restrict__ WwB,
    const float* __restrict__ rf, float* __restrict__ vv,
    const float* __restrict__ obs, const float* __restrict__ wC,
    const float* __restrict__ wQ, const float* __restrict__ wCQ,
    u16* __restrict__ obsW, float* __restrict__ a_o, float* __restrict__ d_o,
    u16* __restrict__ obsT) {
  int bid = blockIdx.x, t = threadIdx.x;
  __shared__ float sa[4], sd[4];
  __shared__ u16 tile[32][33];
  if (bid < 64) {                       // linW f32 -> bf16 (v4)
    int i = bid * 256 + t;
    float4 f = ((const float4*)linW)[i];
    ushort4 o;
    o.x = f2u(f.x); o.y = f2u(f.y); o.z = f2u(f.z); o.w = f2u(f.w);
    ((ushort4*)linWb)[i] = o;
  } else if (bid < 144) {               // WbB[r][k][d] = bf16(Wb[k][r*256+d]), d<128
    int rk = (bid - 64) * 2 + (t >> 7);
    int d = t & 127;
    int r = rk / NB, k = rk % NB;
    WbB[(long)rk * 128 + d] = f2u(Wb[(long)k * KWB + r * 256 + d]);
  } else if (bid < 160) {               // WwB[h][kb] padded to 32
    int idx = (bid - 144) * 256 + t;    // 4096
    int h = idx >> 5, kb = idx & 31;
    WwB[idx] = (kb < NB) ? f2u(Ww[h * NB + kb]) : (u16)0;
  } else if (bid < 1440) {              // vv: wave per (b,r,k)
    int w = t >> 6, lane = t & 63;
    int gid = (bid - 160) * 4 + w;      // 0..5119
    int b = gid / (R * NB), rk = gid % (R * NB), r = rk / NB, k = rk % NB;
    float s = 0.f;
    for (int dd = 0; dd < 2; ++dd) {
      int d = lane + dd * 64;
      s += rf[((long)b * R + r) * H + d] * Wb[(long)k * KWB + r * 256 + 128 + d];
    }
    s = wredsum(s);
    if (lane == 0) vv[((long)b * R + r) * NB + k] = s;
  } else if (bid < 5536) {              // obs prep: 2 rows per block
    int row = (bid - 1440) * 2 + (t >> 7);  // b*Q + o
    int tt = t & 127;
    float x = obs[(long)row * H + tt];
    obsW[(long)row * H + tt] = f2u(x * wCQ[tt]);
    float aa = wredsum(x * wC[tt]);
    float dd2 = wredsum(x * wQ[tt]);
    int wv = t >> 6;
    if ((t & 63) == 0) { sa[wv] = aa; sd[wv] = dd2; }
    __syncthreads();
    if ((t & 127) == 0) {
      int h = t >> 7;
      a_o[row] = sa[h * 2] + sa[h * 2 + 1];
      d_o[row] = sd[h * 2] + sd[h * 2 + 1];
    }
  } else {                              // obsT: 32x32 transpose tiles (1024 blocks)
    int id = bid - 5536;
    int cx = id & 3, ry = (id >> 2) & 7, b = id >> 5;
    int c0 = cx * 32, r0 = ry * 32;
    int tx = t & 31, ty = t >> 5;  // 32 x 8
    for (int i = 0; i < 4; i++) {
      int r = r0 + ty + i * 8, c = c0 + tx;
      tile[ty + i * 8][tx] = f2u(obs[((long)b * Q + r) * H + c]);
    }
    __syncthreads();
    for (int i = 0; i < 4; i++) {
      int c = c0 + ty + i * 8, r = r0 + tx;
      obsT[((long)b * H + c) * Q + r] = tile[tx][ty + i * 8];
    }
  }
}

// ---------------- generic batched MFMA GEMM (used for tT only)
template <bool AF32, bool BF32, int CMODE, bool TRANSC, int BMODE, bool RGRID, int UNROLL>
__global__ __launch_bounds__(64) void gemm_bt(const void* __restrict__ Av, const void* __restrict__ Btv,
                                              void* __restrict__ Cp, float* __restrict__ C2,
                                              const float* __restrict__ bias,
                                              int Mdim, int Ndim, int Kdim,
                                              long sA, long sBt, long sC, long sC2) {
  int batch = blockIdx.y;
  int ab = batch, bb = batch;
  if (RGRID) { ab = batch % R; bb = batch / R; }
  int ntn = Ndim >> 4;
  int mt = blockIdx.x / ntn, nt = blockIdx.x % ntn;
  int lane = threadIdx.x;
  int rw = lane & 15, kq = lane >> 4;
  long aoff = (long)ab * sA + (long)(mt * 16 + rw) * Kdim + kq * 8;
  long boff = (long)bb * sBt + (long)(nt * 16 + rw) * Kdim + kq * 8;
  f32x4 acc = {0.f, 0.f, 0.f, 0.f};
#pragma unroll UNROLL
  for (int k = 0; k < Kdim; k += 32) {
    short8 av, bv;
    if (AF32) av = cvt8((const float*)Av + aoff + k);
    else      av = *(const short8*)((const u16*)Av + aoff + k);
    if (BF32) bv = cvt8((const float*)Btv + boff + k);
    else      bv = *(const short8*)((const u16*)Btv + boff + k);
    acc = __builtin_amdgcn_mfma_f32_16x16x32_bf16(av, bv, acc, 0, 0, 0);
  }
  int gc = nt * 16 + rw;
  float cb = (BMODE == 1) ? bias[gc] : 0.f;
  for (int i = 0; i < 4; i++) {
    int gr = mt * 16 + (kq * 4 + i);
    float val = acc[i] + cb;
    if (BMODE == 2) val += bias[(long)batch * NB + gr];
    if (CMODE == 2) {
      ((float*)Cp)[(long)batch * sC + (long)gr * Ndim + gc] = val;
      C2[(long)batch * sC2 + (long)gc * Mdim + gr] = val;
    } else {
      long idx = TRANSC ? ((long)gc * Mdim + gr) : ((long)gr * Ndim + gc);
      if (CMODE == 1) ((float*)Cp)[(long)batch * sC + idx] = val;
      else            ((u16*)Cp)[(long)batch * sC + idx] = f2u(val);
    }
  }
}

// ---------------- RGCN mega-kernel: h = sum_r adj[b,r] @ t[b,r]; nr = sigmoid(h@Ww^T+rb);
// writes nr, nrT, b_n, c_n.  grid (N/16, B), 256 threads (4 waves).
__global__ __launch_bounds__(256) void k_rgcn(
    const float* __restrict__ adj, const u16* __restrict__ tT,
    const u16* __restrict__ WwB, const float* __restrict__ rb,
    const float* __restrict__ wC, const float* __restrict__ wQ,
    u16* __restrict__ nr, u16* __restrict__ nrT,
    float* __restrict__ b_n, float* __restrict__ c_n) {
  int ntile = blockIdx.x, b = blockIdx.y;
  int n0 = ntile * 16;
  int tid = threadIdx.x;
  int w = tid >> 6, lane = tid & 63;
  int rw = lane & 15, kq = lane >> 4;
  __shared__ float hred[4][16][17];
  __shared__ __align__(16) u16 hbf[16][32];
  __shared__ float bpc[4][16][2];
  float rbv = rb[0];

  f32x4 acc = {0.f, 0.f, 0.f, 0.f};
#pragma unroll 4
  for (int j = 0; j < 40; ++j) {
    int kkk = w + 4 * j;
    int r = kkk >> 4, k = (kkk & 15) * 32;
    short8 av = cvt8(adj + (((long)(b * R + r) * N) + n0 + rw) * N + k + kq * 8);
    short8 bv = *(const short8*)(tT + ((long)(b * R + r) * NB + rw) * N + k + kq * 8);
    acc = __builtin_amdgcn_mfma_f32_16x16x32_bf16(av, bv, acc, 0, 0, 0);
  }
  for (int i = 0; i < 4; i++) hred[w][kq * 4 + i][rw] = acc[i];
  __syncthreads();
  {
    int n = tid >> 4, kb = tid & 15;
    float s = hred[0][n][kb] + hred[1][n][kb] + hred[2][n][kb] + hred[3][n][kb];
    hbf[n][kb] = f2u(s);
    hbf[n][kb + 16] = 0;
  }
  __syncthreads();

  float bsum[4] = {0.f, 0.f, 0.f, 0.f}, csum[4] = {0.f, 0.f, 0.f, 0.f};
  for (int half = 0; half < 2; ++half) {
    int nt = w * 2 + half;
    short8 av = *(const short8*)&hbf[rw][kq * 8];
    short8 bv = *(const short8*)(WwB + (long)(nt * 16 + rw) * 32 + kq * 8);
    f32x4 a2 = {0.f, 0.f, 0.f, 0.f};
    a2 = __builtin_amdgcn_mfma_f32_16x16x32_bf16(av, bv, a2, 0, 0, 0);
    int h = nt * 16 + rw;
    float wq = wQ[h], wc = wC[h];
    for (int i = 0; i < 4; i++) {
      float s = 1.f / (1.f + expf(-(a2[i] + rbv)));
      int n = n0 + kq * 4 + i;
      u16 sv = f2u(s);
      nr[((long)b * N + n) * H + h] = sv;
      nrT[((long)b * H + h) * N + n] = sv;
      bsum[i] += s * wq;
      csum[i] += s * wc;
    }
  }
  for (int i = 0; i < 4; i++) {
    for (int o = 8; o; o >>= 1) { bsum[i] += __shfl_xor(bsum[i], o); csum[i] += __shfl_xor(csum[i], o); }
  }
  if (rw == 0)
    for (int i = 0; i < 4; i++) { bpc[w][kq * 4 + i][0] = bsum[i]; bpc[w][kq * 4 + i][1] = csum[i]; }
  __syncthreads();
  if (tid < 32) {
    int ns = tid & 15, which = tid >> 4;
    float s = bpc[0][ns][which] + bpc[1][ns][which] + bpc[2][ns][which] + bpc[3][ns][which];
    (which ? c_n : b_n)[(long)b * N + n0 + ns] = s;
  }
}

// ---------------- Mm GEMM: S = obsW @ nr^T (bf16), dual write S + ST. 16x128 wave tile.
__global__ __launch_bounds__(64) void k_mm(const u16* __restrict__ obsW, const u16* __restrict__ nr,
                                           u16* __restrict__ S, u16* __restrict__ ST) {
  int bx = blockIdx.x;              // (Q/16) * (N/128) = 64
  int mt = bx >> 2, ng = bx & 3;
  int b = blockIdx.y;
  int lane = threadIdx.x;
  int rw = lane & 15, kq = lane >> 4;
  const u16* ap = obsW + ((long)b * Q + mt * 16 + rw) * H + kq * 8;
  const u16* bp = nr + ((long)b * N + ng * 128 + rw) * H + kq * 8;
  f32x4 acc[8] = {};
  for (int k = 0; k < H; k += 32) {
    short8 av = *(const short8*)(ap + k);
#pragma unroll
    for (int nt = 0; nt < 8; nt++) {
      short8 bv = *(const short8*)(bp + (long)nt * 16 * H + k);
      acc[nt] = __builtin_amdgcn_mfma_f32_16x16x32_bf16(av, bv, acc[nt], 0, 0, 0);
    }
  }
#pragma unroll
  for (int nt = 0; nt < 8; nt++) {
    int gc = ng * 128 + nt * 16 + rw;
    for (int i = 0; i < 4; i++) {
      int gr = mt * 16 + kq * 4 + i;
      u16 v = f2u(acc[nt][i]);
      S[((long)b * Q + gr) * N + gc] = v;
      ST[((long)b * N + gc) * Q + gr] = v;
    }
  }
}

// ---------------- combined softmax on bf16 S/ST
__global__ __launch_bounds__(256) void k_soft_both(
    const u16* __restrict__ S, const u16* __restrict__ ST,
    const float* __restrict__ b_n, const float* __restrict__ c_n,
    const float* __restrict__ a_o, const float* __restrict__ d_o,
    const float* __restrict__ nmask, const float* __restrict__ omask,
    u16* __restrict__ sq1, u16* __restrict__ sc2,
    u16* __restrict__ sc1T, u16* __restrict__ sq2) {
  int bid = blockIdx.x;
  __shared__ float s1a[4], s2a[4];
  if (bid < B * Q) {
    int b = bid / Q;
    int t = threadIdx.x;
    long ro = bid;
    float v1[2], v2[2];
    for (int i = 0; i < 2; i++) {
      int n = t + 256 * i;
      float mv = u2f(S[ro * N + n]);
      bool on = nmask[(long)b * N + n] > 0.f;
      v1[i] = on ? b_n[(long)b * N + n] + mv : -1e30f;
      v2[i] = on ? c_n[(long)b * N + n] + mv : -1e30f;
    }
    float m1 = wredmax(fmaxf(v1[0], v1[1]));
    float m2 = wredmax(fmaxf(v2[0], v2[1]));
    int wv = t >> 6;
    if ((t & 63) == 0) { s1a[wv] = m1; s2a[wv] = m2; }
    __syncthreads();
    m1 = fmaxf(fmaxf(s1a[0], s1a[1]), fmaxf(s1a[2], s1a[3]));
    m2 = fmaxf(fmaxf(s2a[0], s2a[1]), fmaxf(s2a[2], s2a[3]));
    __syncthreads();
    float e1[2], e2[2];
    e1[0] = expf(v1[0] - m1); e1[1] = expf(v1[1] - m1);
    e2[0] = expf(v2[0] - m2); e2[1] = expf(v2[1] - m2);
    float s1 = wredsum(e1[0] + e1[1]);
    float s2 = wredsum(e2[0] + e2[1]);
    if ((t & 63) == 0) { s1a[wv] = s1; s2a[wv] = s2; }
    __syncthreads();
    float r1 = 1.f / (s1a[0] + s1a[1] + s1a[2] + s1a[3]);
    float r2 = 1.f / (s2a[0] + s2a[1] + s2a[2] + s2a[3]);
    for (int i = 0; i < 2; i++) {
      int n = t + 256 * i;
      sq1[ro * N + n] = f2u(e1[i] * r1);
      sc2[ro * N + n] = f2u(e2[i] * r2);
    }
  } else {
    int id = bid - B * Q;
    int b = id / N;
    int o = threadIdx.x;
    long rn = id;
    float mv = u2f(ST[rn * Q + o]);
    bool on = omask[(long)b * Q + o] > 0.f;
    float v1 = on ? a_o[(long)b * Q + o] + mv : -1e30f;
    float v2 = on ? d_o[(long)b * Q + o] + mv : -1e30f;
    float m1 = wredmax(v1), m2 = wredmax(v2);
    int wv = o >> 6;
    if ((o & 63) == 0) { s1a[wv] = m1; s2a[wv] = m2; }
    __syncthreads();
    m1 = fmaxf(fmaxf(s1a[0], s1a[1]), fmaxf(s1a[2], s1a[3]));
    m2 = fmaxf(fmaxf(s2a[0], s2a[1]), fmaxf(s2a[2], s2a[3]));
    __syncthreads();
    float e1 = expf(v1 - m1), e2 = expf(v2 - m2);
    float s1 = wredsum(e1), s2 = wredsum(e2);
    if ((o & 63) == 0) { s1a[wv] = s1; s2a[wv] = s2; }
    __syncthreads();
    float r1 = 1.f / (s1a[0] + s1a[1] + s1a[2] + s1a[3]);
    float r2 = 1.f / (s2a[0] + s2a[1] + s2a[2] + s2a[3]);
    sc1T[rn * Q + o] = f2u(e1 * r1);
    sq2[rn * Q + o] = f2u(e2 * r2);
  }
}

// ---------------- z-multiplexed bf16 GEMMs, 16x128 wave tile (Ndim = H = 128)
struct GPar {
  const u16* A; const u16* Bt; u16* C;
  int Mdim; int Kdim; long sA, sBt, sC; int tc;
};
__global__ __launch_bounds__(64) void gemm_quad8(GPar p0, GPar p1, GPar p2, GPar p3) {
  int z = blockIdx.z;
  GPar p = (z == 0) ? p0 : (z == 1) ? p1 : (z == 2) ? p2 : p3;
  int mt = blockIdx.x;
  if (mt * 16 >= p.Mdim) return;
  int batch = blockIdx.y;
  int lane = threadIdx.x;
  int rw = lane & 15, kq = lane >> 4;
  const u16* ap = p.A + (long)batch * p.sA + (long)(mt * 16 + rw) * p.Kdim + kq * 8;
  const u16* bp = p.Bt + (long)batch * p.sBt + (long)rw * p.Kdim + kq * 8;
  f32x4 acc[8] = {};
  for (int k = 0; k < p.Kdim; k += 32) {
    short8 av = *(const short8*)(ap + k);
#pragma unroll
    for (int nt = 0; nt < 8; nt++) {
      short8 bv = *(const short8*)(bp + (long)nt * 16 * p.Kdim + k);
      acc[nt] = __builtin_amdgcn_mfma_f32_16x16x32_bf16(av, bv, acc[nt], 0, 0, 0);
    }
  }
#pragma unroll
  for (int nt = 0; nt < 8; nt++) {
    int gc = nt * 16 + rw;
    for (int i = 0; i < 4; i++) {
      int gr = mt * 16 + kq * 4 + i;
      long idx = p.tc ? ((long)gc * p.Mdim + gr) : ((long)gr * H + gc);
      p.C[(long)batch * p.sC + idx] = f2u(acc[nt][i]);
    }
  }
}

// ---------------- fused concat + output linear, z: 0=obs-side (f32 X), 1=nr-side (bf16 X)
__global__ __launch_bounds__(64) void gemm_cat2(
    const float* __restrict__ obs, const u16* __restrict__ nrr,
    const u16* __restrict__ P1, const u16* __restrict__ Qm1,
    const u16* __restrict__ P2, const u16* __restrict__ Qm2,
    const u16* __restrict__ Wt, const float* __restrict__ bias,
    float* __restrict__ out0, float* __restrict__ out1) {
  int z = blockIdx.z;
  int Mdim = z ? N : Q;
  int mt = blockIdx.x;
  if (mt * 16 >= Mdim) return;
  int batch = blockIdx.y;
  const u16* P = z ? P2 : P1;
  const u16* Qm = z ? Qm2 : Qm1;
  float* out = z ? out1 : out0;
  int lane = threadIdx.x;
  int rw = lane & 15, kq = lane >> 4;
  long arow = (long)batch * Mdim + mt * 16 + rw;
  const u16* bp = Wt + (long)rw * (4 * H) + kq * 8;
  f32x4 acc[8] = {};
  for (int k = 0; k < 4 * H; k += 32) {
    int sec = k >> 7;
    int off = (k & 127) + kq * 8;
    long rb2 = arow * H + off;
    short8 av;
    if (sec == 0) {
      if (!z) av = cvt8(obs + rb2);
      else    av = *(const short8*)(nrr + rb2);
    } else if (sec == 1) {
      av = *(const short8*)(P + rb2);
    } else {
      float xf[8];
      if (!z) {
        const float* xp = obs + rb2;
        float4 f0 = *(const float4*)xp;
        float4 f1 = *(const float4*)(xp + 4);
        xf[0] = f0.x; xf[1] = f0.y; xf[2] = f0.z; xf[3] = f0.w;
        xf[4] = f1.x; xf[5] = f1.y; xf[6] = f1.z; xf[7] = f1.w;
      } else {
        short8 xv = *(const short8*)(nrr + rb2);
        for (int i = 0; i < 8; i++) xf[i] = u2f((u16)xv[i]);
      }
      short8 pv = *(const short8*)((sec == 2 ? P : Qm) + rb2);
      for (int i = 0; i < 8; i++) av[i] = (short)f2u(xf[i] * u2f((u16)pv[i]));
    }
#pragma unroll
    for (int nt = 0; nt < 8; nt++) {
      short8 bv = *(const short8*)(bp + (long)nt * 16 * (4 * H) + k);
      acc[nt] = __builtin_amdgcn_mfma_f32_16x16x32_bf16(av, bv, acc[nt], 0, 0, 0);
    }
  }
#pragma unroll
  for (int nt = 0; nt < 8; nt++) {
    int gc = nt * 16 + rw;
    float cb = bias[gc];
    for (int i = 0; i < 4; i++) {
      int gr = mt * 16 + kq * 4 + i;
      out[((long)batch * Mdim + gr) * H + gc] = acc[nt][i] + cb;
    }
  }
}

// ---------------- launch ----------------
extern "C" void kernel_launch(void* const* d_in, const int* in_sizes, int n_in,
                              void* d_out, int out_size, void* d_ws, size_t ws_size,
                              hipStream_t stream) {
  const float* nf    = (const float*)d_in[0];
  const float* rf    = (const float*)d_in[1];
  const float* adj   = (const float*)d_in[2];
  const float* obs   = (const float*)d_in[3];
  const float* nmask = (const float*)d_in[4];
  const float* omask = (const float*)d_in[5];
  const float* Wb    = (const float*)d_in[6];
  const float* Ww    = (const float*)d_in[7];
  const float* rb    = (const float*)d_in[8];
  const float* wC    = (const float*)d_in[9];
  const float* wQ    = (const float*)d_in[10];
  const float* wCQ   = (const float*)d_in[11];
  // d_in[12] = cq_bias: uniform shift along both softmax axes -> cancels, unused
  const float* linW  = (const float*)d_in[13];
  const float* linb  = (const float*)d_in[14];
  float* outp = (float*)d_out;

  char* w = (char*)d_ws;
  auto alloc = [&](size_t bytes) { char* p = w; w += (bytes + 255) & ~(size_t)255; return p; };
  u16*   linWb = (u16*)  alloc((size_t)H * 4 * H * 2);
  u16*   WbB   = (u16*)  alloc((size_t)R * NB * 128 * 2);
  u16*   WwB   = (u16*)  alloc((size_t)H * 32 * 2);
  float* vv    = (float*)alloc((size_t)B * R * NB * 4);
  u16*   obsW  = (u16*)  alloc((size_t)B * Q * H * 2);
  u16*   obsT  = (u16*)  alloc((size_t)B * H * Q * 2);
  float* a_o   = (float*)alloc((size_t)B * Q * 4);
  float* d_o   = (float*)alloc((size_t)B * Q * 4);
  float* b_n   = (float*)alloc((size_t)B * N * 4);
  float* c_n   = (float*)alloc((size_t)B * N * 4);
  u16*   nr    = (u16*)  alloc((size_t)B * N * H * 2);
  u16*   nrT   = (u16*)  alloc((size_t)B * H * N * 2);
  u16*   tT    = (u16*)  alloc((size_t)B * R * NB * N * 2);
  u16*   S     = (u16*)  alloc((size_t)B * Q * N * 2);
  u16*   ST    = (u16*)  alloc((size_t)B * N * Q * 2);
  u16*   sq1   = (u16*)  alloc((size_t)B * Q * N * 2);
  u16*   sc2   = (u16*)  alloc((size_t)B * Q * N * 2);
  u16*   sc1T  = (u16*)  alloc((size_t)B * N * Q * 2);
  u16*   sq2   = (u16*)  alloc((size_t)B * N * Q * 2);
  u16*   P1    = (u16*)  alloc((size_t)B * Q * H * 2);
  u16*   T1T   = (u16*)  alloc((size_t)B * H * N * 2);
  u16*   Qm1   = (u16*)  alloc((size_t)B * Q * H * 2);
  u16*   P2    = (u16*)  alloc((size_t)B * N * H * 2);
  u16*   T2T   = (u16*)  alloc((size_t)B * H * Q * 2);
  u16*   Qm2   = (u16*)  alloc((size_t)B * N * H * 2);

  // 1. prep (incl. obs transpose)
  k_prep<<<6560, 256, 0, stream>>>(linW, linWb, Wb, WbB, Ww, WwB,
                                   rf, vv, obs, wC, wQ, wCQ, obsW, a_o, d_o, obsT);
  // 2. tT[b,r](16 x N) = WbB[r](16 x 128) @ nf[b]^T + v[b,r]
  gemm_bt<false, true, 0, false, 2, true, 2><<<dim3(N / 16, B * R), 64, 0, stream>>>(
      WbB, nf, tT, nullptr, vv, NB, N, H, (long)NB * 128, (long)N * H, (long)NB * N, 0);
  // 3. mega: h = sum_r adj@t ; nr,nrT = sigmoid(...); b_n; c_n
  k_rgcn<<<dim3(N / 16, B), 256, 0, stream>>>(adj, tT, WwB, rb, wC, wQ, nr, nrT, b_n, c_n);
  // 4. S = obsW @ nr^T (bf16, dual write)
  k_mm<<<dim3((Q / 16) * (N / 128), B), 64, 0, stream>>>(obsW, nr, S, ST);
  // 5. fused masked softmaxes
  k_soft_both<<<B * Q + B * N, 256, 0, stream>>>(S, ST, b_n, c_n, a_o, d_o, nmask, omask,
                                                 sq1, sc2, sc1T, sq2);
  // 6. four attention GEMMs
  GPar pP1  = {sq1,  nrT,  P1,  Q, N, (long)Q * N, (long)H * N, (long)Q * H, 0};
  GPar pT2T = {sc2,  nrT,  T2T, Q, N, (long)Q * N, (long)H * N, (long)H * Q, 1};
  GPar pT1T = {sc1T, obsT, T1T, N, Q, (long)N * Q, (long)H * Q, (long)H * N, 1};
  GPar pP2  = {sq2,  obsT, P2,  N, Q, (long)N * Q, (long)H * Q, (long)N * H, 0};
  gemm_quad8<<<dim3(N / 16, B, 4), 64, 0, stream>>>(pP1, pT2T, pT1T, pP2);
  // 7. Qm pair
  GPar pQm1 = {sq1, T1T, Qm1, Q, N, (long)Q * N, (long)H * N, (long)Q * H, 0};
  GPar pQm2 = {sq2, T2T, Qm2, N, Q, (long)N * Q, (long)H * Q, (long)N * H, 0};
  gemm_quad8<<<dim3(N / 16, B, 2), 64, 0, stream>>>(pQm1, pQm2, pQm1, pQm2);
  // 8. fused concat + output linear (both sides)
  gemm_cat2<<<dim3(N / 16, B, 2), 64, 0, stream>>>(obs, nr, P1, Qm1, P2, Qm2,
                                                   linWb, linb, outp, outp + (long)B * Q * H);

  (void)in_sizes; (void)n_in; (void)out_size; (void)ws_size;
}

// Round 7
// 282.369 us; speedup vs baseline: 1.9734x; 1.0539x over previous
//
#include <hip/hip_runtime.h>
#include <hip/hip_bf16.h>
#include <stdint.h>

typedef unsigned short u16;
typedef __attribute__((ext_vector_type(8))) short short8;
typedef __attribute__((ext_vector_type(4))) float f32x4;

#define DEVI static __device__ __forceinline__

constexpr int B = 32, R = 10, N = 512, H = 128, Q = 256, NB = 16;
constexpr int KWB = 2560;  // (DN+DR)*R

DEVI u16 f2u(float f) { return __builtin_bit_cast(unsigned short, __float2bfloat16(f)); }
DEVI float u2f(u16 u) { union { uint32_t i; float f; } c; c.i = ((uint32_t)u) << 16; return c.f; }

DEVI float wredmax(float v) { for (int o = 32; o; o >>= 1) v = fmaxf(v, __shfl_xor(v, o)); return v; }
DEVI float wredsum(float v) { for (int o = 32; o; o >>= 1) v += __shfl_xor(v, o); return v; }

DEVI short8 cvt8(const float* p) {
  float4 f0 = *(const float4*)p;
  float4 f1 = *(const float4*)(p + 4);
  short8 v;
  v[0] = (short)f2u(f0.x); v[1] = (short)f2u(f0.y);
  v[2] = (short)f2u(f0.z); v[3] = (short)f2u(f0.w);
  v[4] = (short)f2u(f1.x); v[5] = (short)f2u(f1.y);
  v[6] = (short)f2u(f1.z); v[7] = (short)f2u(f1.w);
  return v;
}

// ---------------- merged prep: linWb | WbB | WwB(pad32) | vv | obs_prep | obsT ----------------
__global__ __launch_bounds__(256) void k_prep(
    const float* __restrict__ linW, u16* __restrict__ linWb,
    const float* __restrict__ Wb, u16* __restrict__ WbB,
    const float* __restrict__ Ww, u16* __restrict__ WwB,
    const float* __restrict__ rf, float* __restrict__ vv,
    const float* __restrict__ obs, const float* __restrict__ wC,
    const float* __restrict__ wQ, const float* __restrict__ wCQ,
    u16* __restrict__ obsW, float* __restrict__ a_o, float* __restrict__ d_o,
    u16* __restrict__ obsT) {
  int bid = blockIdx.x, t = threadIdx.x;
  __shared__ float sa[4], sd[4];
  __shared__ u16 tile[32][33];
  if (bid < 64) {                       // linW f32 -> bf16 (v4)
    int i = bid * 256 + t;
    float4 f = ((const float4*)linW)[i];
    ushort4 o;
    o.x = f2u(f.x); o.y = f2u(f.y); o.z = f2u(f.z); o.w = f2u(f.w);
    ((ushort4*)linWb)[i] = o;
  } else if (bid < 144) {               // WbB[r][k][d] = bf16(Wb[k][r*256+d]), d<128
    int rk = (bid - 64) * 2 + (t >> 7);
    int d = t & 127;
    int r = rk / NB, k = rk % NB;
    WbB[(long)rk * 128 + d] = f2u(Wb[(long)k * KWB + r * 256 + d]);
  } else if (bid < 160) {               // WwB[h][kb] padded to 32
    int idx = (bid - 144) * 256 + t;    // 4096
    int h = idx >> 5, kb = idx & 31;
    WwB[idx] = (kb < NB) ? f2u(Ww[h * NB + kb]) : (u16)0;
  } else if (bid < 1440) {              // vv: wave per (b,r,k)
    int w = t >> 6, lane = t & 63;
    int gid = (bid - 160) * 4 + w;      // 0..5119
    int b = gid / (R * NB), rk = gid % (R * NB), r = rk / NB, k = rk % NB;
    float s = 0.f;
    for (int dd = 0; dd < 2; ++dd) {
      int d = lane + dd * 64;
      s += rf[((long)b * R + r) * H + d] * Wb[(long)k * KWB + r * 256 + 128 + d];
    }
    s = wredsum(s);
    if (lane == 0) vv[((long)b * R + r) * NB + k] = s;
  } else if (bid < 5536) {              // obs prep: 2 rows per block
    int row = (bid - 1440) * 2 + (t >> 7);  // b*Q + o
    int tt = t & 127;
    float x = obs[(long)row * H + tt];
    obsW[(long)row * H + tt] = f2u(x * wCQ[tt]);
    float aa = wredsum(x * wC[tt]);
    float dd2 = wredsum(x * wQ[tt]);
    int wv = t >> 6;
    if ((t & 63) == 0) { sa[wv] = aa; sd[wv] = dd2; }
    __syncthreads();
    if ((t & 127) == 0) {
      int h = t >> 7;
      a_o[row] = sa[h * 2] + sa[h * 2 + 1];
      d_o[row] = sd[h * 2] + sd[h * 2 + 1];
    }
  } else {                              // obsT: 32x32 transpose tiles (1024 blocks)
    int id = bid - 5536;
    int cx = id & 3, ry = (id >> 2) & 7, b = id >> 5;
    int c0 = cx * 32, r0 = ry * 32;
    int tx = t & 31, ty = t >> 5;  // 32 x 8
    for (int i = 0; i < 4; i++) {
      int r = r0 + ty + i * 8, c = c0 + tx;
      tile[ty + i * 8][tx] = f2u(obs[((long)b * Q + r) * H + c]);
    }
    __syncthreads();
    for (int i = 0; i < 4; i++) {
      int c = c0 + ty + i * 8, r = r0 + tx;
      obsT[((long)b * H + c) * Q + r] = tile[tx][ty + i * 8];
    }
  }
}

// ---------------- k_tt: tT[b,r](16 x N) = WbB[r] @ nf[b]^T + vv[b,r]
// nf[b] 128-row chunk staged ONCE in LDS (bf16, XOR-swizzled), all R computed in-block.
__global__ __launch_bounds__(512) void k_tt(const u16* __restrict__ WbB, const float* __restrict__ nf,
                                            const float* __restrict__ vv, u16* __restrict__ tT) {
  int bx = blockIdx.x, b = blockIdx.y;   // bx: n-chunk of 128
  int t = threadIdx.x;
  __shared__ __align__(16) u16 tile[128][128];  // 32 KB
  {
    int row = t >> 2, q = (t & 3) * 32;
    const float* src = nf + ((long)b * N + bx * 128 + row) * H + q;
    int sw = (row & 7) << 3;
    for (int j = 0; j < 4; j++) {
      short8 v = cvt8(src + j * 8);
      *(short8*)&tile[row][(q + j * 8) ^ sw] = v;
    }
  }
  __syncthreads();
  int w = t >> 6, lane = t & 63;
  int rw = lane & 15, kq = lane >> 4;
  for (int r = w; r < R; r += 8) {
    f32x4 acc[8] = {};
    for (int kit = 0; kit < H; kit += 32) {
      short8 av = *(const short8*)(WbB + ((long)r * NB + rw) * 128 + kit + kq * 8);
#pragma unroll
      for (int nt = 0; nt < 8; nt++) {
        int brow = nt * 16 + rw;
        short8 bv = *(const short8*)&tile[brow][(kit + kq * 8) ^ ((brow & 7) << 3)];
        acc[nt] = __builtin_amdgcn_mfma_f32_16x16x32_bf16(av, bv, acc[nt], 0, 0, 0);
      }
    }
    long rbase = (long)(b * R + r) * NB;
#pragma unroll
    for (int nt = 0; nt < 8; nt++) {
      int gc = bx * 128 + nt * 16 + rw;
      for (int i = 0; i < 4; i++) {
        int gr = kq * 4 + i;
        tT[(rbase + gr) * N + gc] = f2u(acc[nt][i] + vv[rbase + gr]);
      }
    }
  }
}

// ---------------- RGCN mega-kernel (8 waves): h = sum_r adj[b,r] @ t[b,r];
// nr = sigmoid(h@Ww^T+rb); writes nr, nrT, b_n, c_n.  grid (N/16, B), 512 threads.
__global__ __launch_bounds__(512) void k_rgcn(
    const float* __restrict__ adj, const u16* __restrict__ tT,
    const u16* __restrict__ WwB, const float* __restrict__ rb,
    const float* __restrict__ wC, const float* __restrict__ wQ,
    u16* __restrict__ nr, u16* __restrict__ nrT,
    float* __restrict__ b_n, float* __restrict__ c_n) {
  int ntile = blockIdx.x, b = blockIdx.y;
  int n0 = ntile * 16;
  int tid = threadIdx.x;
  int w = tid >> 6, lane = tid & 63;
  int rw = lane & 15, kq = lane >> 4;
  __shared__ float hred[8][16][17];
  __shared__ __align__(16) u16 hbf[16][32];
  __shared__ float bpc[8][16][2];
  float rbv = rb[0];

  f32x4 acc = {0.f, 0.f, 0.f, 0.f};
#pragma unroll 4
  for (int j = 0; j < 20; ++j) {
    int kkk = w + 8 * j;
    int r = kkk >> 4, k = (kkk & 15) * 32;
    short8 av = cvt8(adj + (((long)(b * R + r) * N) + n0 + rw) * N + k + kq * 8);
    short8 bv = *(const short8*)(tT + ((long)(b * R + r) * NB + rw) * N + k + kq * 8);
    acc = __builtin_amdgcn_mfma_f32_16x16x32_bf16(av, bv, acc, 0, 0, 0);
  }
  for (int i = 0; i < 4; i++) hred[w][kq * 4 + i][rw] = acc[i];
  __syncthreads();
  if (tid < 256) {
    int n = tid >> 4, kb = tid & 15;
    float s = 0.f;
    for (int ww = 0; ww < 8; ww++) s += hred[ww][n][kb];
    hbf[n][kb] = f2u(s);
    hbf[n][kb + 16] = 0;
  }
  __syncthreads();

  // phase 2: wave w handles h-col tile nt = w
  short8 av = *(const short8*)&hbf[rw][kq * 8];
  short8 bv = *(const short8*)(WwB + (long)(w * 16 + rw) * 32 + kq * 8);
  f32x4 a2 = {0.f, 0.f, 0.f, 0.f};
  a2 = __builtin_amdgcn_mfma_f32_16x16x32_bf16(av, bv, a2, 0, 0, 0);
  int h = w * 16 + rw;
  float wq = wQ[h], wc = wC[h];
  float bsum[4], csum[4];
  for (int i = 0; i < 4; i++) {
    float s = 1.f / (1.f + expf(-(a2[i] + rbv)));
    int n = n0 + kq * 4 + i;
    u16 sv = f2u(s);
    nr[((long)b * N + n) * H + h] = sv;
    nrT[((long)b * H + h) * N + n] = sv;
    bsum[i] = s * wq;
    csum[i] = s * wc;
  }
  for (int i = 0; i < 4; i++) {
    for (int o = 8; o; o >>= 1) { bsum[i] += __shfl_xor(bsum[i], o); csum[i] += __shfl_xor(csum[i], o); }
  }
  if (rw == 0)
    for (int i = 0; i < 4; i++) { bpc[w][kq * 4 + i][0] = bsum[i]; bpc[w][kq * 4 + i][1] = csum[i]; }
  __syncthreads();
  if (tid < 32) {
    int ns = tid & 15, which = tid >> 4;
    float s = 0.f;
    for (int ww = 0; ww < 8; ww++) s += bpc[ww][ns][which];
    (which ? c_n : b_n)[(long)b * N + n0 + ns] = s;
  }
}

// ---------------- k_mm_soft: S-tile (16 x 512) in registers; row softmaxes (f32) in-kernel.
// Writes sq1, sc2 (bf16) + ST (bf16, for col pass). grid (Q/16, B), 512 threads (8 waves x 64 cols).
__global__ __launch_bounds__(512) void k_mm_soft(
    const u16* __restrict__ obsW, const u16* __restrict__ nr,
    const float* __restrict__ b_n, const float* __restrict__ c_n,
    const float* __restrict__ nmask,
    u16* __restrict__ sq1, u16* __restrict__ sc2, u16* __restrict__ ST) {
  int mt = blockIdx.x, b = blockIdx.y;
  int tid = threadIdx.x;
  int w = tid >> 6, lane = tid & 63;
  int rw = lane & 15, kq = lane >> 4;
  __shared__ float sm1[8][16], sm2[8][16], ss1[8][16], ss2[8][16];

  const u16* ap = obsW + ((long)b * Q + mt * 16 + rw) * H + kq * 8;
  const u16* bp = nr + ((long)b * N + w * 64 + rw) * H + kq * 8;
  f32x4 acc[4] = {};
  for (int k = 0; k < H; k += 32) {
    short8 av = *(const short8*)(ap + k);
#pragma unroll
    for (int nt = 0; nt < 4; nt++) {
      short8 bv = *(const short8*)(bp + (long)nt * 16 * H + k);
      acc[nt] = __builtin_amdgcn_mfma_f32_16x16x32_bf16(av, bv, acc[nt], 0, 0, 0);
    }
  }
  // per-lane column metadata
  float bn[4], cn[4];
  bool mk[4];
  int gcv[4];
#pragma unroll
  for (int nt = 0; nt < 4; nt++) {
    int gc = w * 64 + nt * 16 + rw;
    gcv[nt] = gc;
    mk[nt] = nmask[(long)b * N + gc] > 0.f;
    bn[nt] = b_n[(long)b * N + gc];
    cn[nt] = c_n[(long)b * N + gc];
  }
  // ST write (pre-softmax S, bf16)
#pragma unroll
  for (int nt = 0; nt < 4; nt++) {
    long stb = ((long)b * N + gcv[nt]) * Q + mt * 16 + kq * 4;
    for (int i = 0; i < 4; i++) ST[stb + i] = f2u(acc[nt][i]);
  }
  // row maxes (rows = kq*4+i)
  float m1[4], m2[4];
  for (int i = 0; i < 4; i++) { m1[i] = -1e30f; m2[i] = -1e30f; }
#pragma unroll
  for (int nt = 0; nt < 4; nt++)
    for (int i = 0; i < 4; i++) {
      float s = acc[nt][i];
      if (mk[nt]) { m1[i] = fmaxf(m1[i], s + bn[nt]); m2[i] = fmaxf(m2[i], s + cn[nt]); }
    }
  for (int i = 0; i < 4; i++)
    for (int o = 8; o; o >>= 1) { m1[i] = fmaxf(m1[i], __shfl_xor(m1[i], o)); m2[i] = fmaxf(m2[i], __shfl_xor(m2[i], o)); }
  if (rw == 0)
    for (int i = 0; i < 4; i++) { sm1[w][kq * 4 + i] = m1[i]; sm2[w][kq * 4 + i] = m2[i]; }
  __syncthreads();
  for (int i = 0; i < 4; i++) {
    float g1 = -1e30f, g2 = -1e30f;
    for (int ww = 0; ww < 8; ww++) { g1 = fmaxf(g1, sm1[ww][kq * 4 + i]); g2 = fmaxf(g2, sm2[ww][kq * 4 + i]); }
    m1[i] = g1; m2[i] = g2;
  }
  // exponentials + row sums
  float e1[4][4], e2[4][4];
  float s1[4] = {0.f, 0.f, 0.f, 0.f}, s2[4] = {0.f, 0.f, 0.f, 0.f};
#pragma unroll
  for (int nt = 0; nt < 4; nt++)
    for (int i = 0; i < 4; i++) {
      float s = acc[nt][i];
      float a = mk[nt] ? expf(s + bn[nt] - m1[i]) : 0.f;
      float c = mk[nt] ? expf(s + cn[nt] - m2[i]) : 0.f;
      e1[nt][i] = a; e2[nt][i] = c;
      s1[i] += a; s2[i] += c;
    }
  for (int i = 0; i < 4; i++)
    for (int o = 8; o; o >>= 1) { s1[i] += __shfl_xor(s1[i], o); s2[i] += __shfl_xor(s2[i], o); }
  if (rw == 0)
    for (int i = 0; i < 4; i++) { ss1[w][kq * 4 + i] = s1[i]; ss2[w][kq * 4 + i] = s2[i]; }
  __syncthreads();
  float r1[4], r2[4];
  for (int i = 0; i < 4; i++) {
    float g1 = 0.f, g2 = 0.f;
    for (int ww = 0; ww < 8; ww++) { g1 += ss1[ww][kq * 4 + i]; g2 += ss2[ww][kq * 4 + i]; }
    r1[i] = 1.f / g1; r2[i] = 1.f / g2;
  }
#pragma unroll
  for (int nt = 0; nt < 4; nt++)
    for (int i = 0; i < 4; i++) {
      long ob = ((long)b * Q + mt * 16 + kq * 4 + i) * N + gcv[nt];
      sq1[ob] = f2u(e1[nt][i] * r1[i]);
      sc2[ob] = f2u(e2[nt][i] * r2[i]);
    }
}

// ---------------- col softmax: per (b,n) read ST row once -> sc1T, sq2
__global__ __launch_bounds__(256) void k_soft_col(
    const u16* __restrict__ ST, const float* __restrict__ a_o, const float* __restrict__ d_o,
    const float* __restrict__ omask, u16* __restrict__ sc1T, u16* __restrict__ sq2) {
  int id = blockIdx.x;
  int b = id / N;
  int o = threadIdx.x;
  long rn = id;
  __shared__ float s1a[4], s2a[4];
  float mv = u2f(ST[rn * Q + o]);
  bool on = omask[(long)b * Q + o] > 0.f;
  float v1 = on ? a_o[(long)b * Q + o] + mv : -1e30f;
  float v2 = on ? d_o[(long)b * Q + o] + mv : -1e30f;
  float m1 = wredmax(v1), m2 = wredmax(v2);
  int wv = o >> 6;
  if ((o & 63) == 0) { s1a[wv] = m1; s2a[wv] = m2; }
  __syncthreads();
  m1 = fmaxf(fmaxf(s1a[0], s1a[1]), fmaxf(s1a[2], s1a[3]));
  m2 = fmaxf(fmaxf(s2a[0], s2a[1]), fmaxf(s2a[2], s2a[3]));
  __syncthreads();
  float e1 = expf(v1 - m1), e2 = expf(v2 - m2);
  float s1 = wredsum(e1), s2 = wredsum(e2);
  if ((o & 63) == 0) { s1a[wv] = s1; s2a[wv] = s2; }
  __syncthreads();
  float r1 = 1.f / (s1a[0] + s1a[1] + s1a[2] + s1a[3]);
  float r2 = 1.f / (s2a[0] + s2a[1] + s2a[2] + s2a[3]);
  sc1T[rn * Q + o] = f2u(e1 * r1);
  sq2[rn * Q + o] = f2u(e2 * r2);
}

// ---------------- z-multiplexed bf16 GEMMs, 16x128 wave tile (Ndim = H = 128)
struct GPar {
  const u16* A; const u16* Bt; u16* C;
  int Mdim; int Kdim; long sA, sBt, sC; int tc;
};
__global__ __launch_bounds__(64) void gemm_quad8(GPar p0, GPar p1, GPar p2, GPar p3) {
  int z = blockIdx.z;
  GPar p = (z == 0) ? p0 : (z == 1) ? p1 : (z == 2) ? p2 : p3;
  int mt = blockIdx.x;
  if (mt * 16 >= p.Mdim) return;
  int batch = blockIdx.y;
  int lane = threadIdx.x;
  int rw = lane & 15, kq = lane >> 4;
  const u16* ap = p.A + (long)batch * p.sA + (long)(mt * 16 + rw) * p.Kdim + kq * 8;
  const u16* bp = p.Bt + (long)batch * p.sBt + (long)rw * p.Kdim + kq * 8;
  f32x4 acc[8] = {};
  for (int k = 0; k < p.Kdim; k += 32) {
    short8 av = *(const short8*)(ap + k);
#pragma unroll
    for (int nt = 0; nt < 8; nt++) {
      short8 bv = *(const short8*)(bp + (long)nt * 16 * p.Kdim + k);
      acc[nt] = __builtin_amdgcn_mfma_f32_16x16x32_bf16(av, bv, acc[nt], 0, 0, 0);
    }
  }
#pragma unroll
  for (int nt = 0; nt < 8; nt++) {
    int gc = nt * 16 + rw;
    for (int i = 0; i < 4; i++) {
      int gr = mt * 16 + kq * 4 + i;
      long idx = p.tc ? ((long)gc * p.Mdim + gr) : ((long)gr * H + gc);
      p.C[(long)batch * p.sC + idx] = f2u(acc[nt][i]);
    }
  }
}

// ---------------- fused concat + output linear, z: 0=obs-side (f32 X), 1=nr-side (bf16 X)
__global__ __launch_bounds__(64) void gemm_cat2(
    const float* __restrict__ obs, const u16* __restrict__ nrr,
    const u16* __restrict__ P1, const u16* __restrict__ Qm1,
    const u16* __restrict__ P2, const u16* __restrict__ Qm2,
    const u16* __restrict__ Wt, const float* __restrict__ bias,
    float* __restrict__ out0, float* __restrict__ out1) {
  int z = blockIdx.z;
  int Mdim = z ? N : Q;
  int mt = blockIdx.x;
  if (mt * 16 >= Mdim) return;
  int batch = blockIdx.y;
  const u16* P = z ? P2 : P1;
  const u16* Qm = z ? Qm2 : Qm1;
  float* out = z ? out1 : out0;
  int lane = threadIdx.x;
  int rw = lane & 15, kq = lane >> 4;
  long arow = (long)batch * Mdim + mt * 16 + rw;
  const u16* bp = Wt + (long)rw * (4 * H) + kq * 8;
  f32x4 acc[8] = {};
  for (int k = 0; k < 4 * H; k += 32) {
    int sec = k >> 7;
    int off = (k & 127) + kq * 8;
    long rb2 = arow * H + off;
    short8 av;
    if (sec == 0) {
      if (!z) av = cvt8(obs + rb2);
      else    av = *(const short8*)(nrr + rb2);
    } else if (sec == 1) {
      av = *(const short8*)(P + rb2);
    } else {
      float xf[8];
      if (!z) {
        const float* xp = obs + rb2;
        float4 f0 = *(const float4*)xp;
        float4 f1 = *(const float4*)(xp + 4);
        xf[0] = f0.x; xf[1] = f0.y; xf[2] = f0.z; xf[3] = f0.w;
        xf[4] = f1.x; xf[5] = f1.y; xf[6] = f1.z; xf[7] = f1.w;
      } else {
        short8 xv = *(const short8*)(nrr + rb2);
        for (int i = 0; i < 8; i++) xf[i] = u2f((u16)xv[i]);
      }
      short8 pv = *(const short8*)((sec == 2 ? P : Qm) + rb2);
      for (int i = 0; i < 8; i++) av[i] = (short)f2u(xf[i] * u2f((u16)pv[i]));
    }
#pragma unroll
    for (int nt = 0; nt < 8; nt++) {
      short8 bv = *(const short8*)(bp + (long)nt * 16 * (4 * H) + k);
      acc[nt] = __builtin_amdgcn_mfma_f32_16x16x32_bf16(av, bv, acc[nt], 0, 0, 0);
    }
  }
#pragma unroll
  for (int nt = 0; nt < 8; nt++) {
    int gc = nt * 16 + rw;
    float cb = bias[gc];
    for (int i = 0; i < 4; i++) {
      int gr = mt * 16 + kq * 4 + i;
      out[((long)batch * Mdim + gr) * H + gc] = acc[nt][i] + cb;
    }
  }
}

// ---------------- launch ----------------
extern "C" void kernel_launch(void* const* d_in, const int* in_sizes, int n_in,
                              void* d_out, int out_size, void* d_ws, size_t ws_size,
                              hipStream_t stream) {
  const float* nf    = (const float*)d_in[0];
  const float* rf    = (const float*)d_in[1];
  const float* adj   = (const float*)d_in[2];
  const float* obs   = (const float*)d_in[3];
  const float* nmask = (const float*)d_in[4];
  const float* omask = (const float*)d_in[5];
  const float* Wb    = (const float*)d_in[6];
  const float* Ww    = (const float*)d_in[7];
  const float* rb    = (const float*)d_in[8];
  const float* wC    = (const float*)d_in[9];
  const float* wQ    = (const float*)d_in[10];
  const float* wCQ   = (const float*)d_in[11];
  // d_in[12] = cq_bias: uniform shift along both softmax axes -> cancels, unused
  const float* linW  = (const float*)d_in[13];
  const float* linb  = (const float*)d_in[14];
  float* outp = (float*)d_out;

  char* w = (char*)d_ws;
  auto alloc = [&](size_t bytes) { char* p = w; w += (bytes + 255) & ~(size_t)255; return p; };
  u16*   linWb = (u16*)  alloc((size_t)H * 4 * H * 2);
  u16*   WbB   = (u16*)  alloc((size_t)R * NB * 128 * 2);
  u16*   WwB   = (u16*)  alloc((size_t)H * 32 * 2);
  float* vv    = (float*)alloc((size_t)B * R * NB * 4);
  u16*   obsW  = (u16*)  alloc((size_t)B * Q * H * 2);
  u16*   obsT  = (u16*)  alloc((size_t)B * H * Q * 2);
  float* a_o   = (float*)alloc((size_t)B * Q * 4);
  float* d_o   = (float*)alloc((size_t)B * Q * 4);
  float* b_n   = (float*)alloc((size_t)B * N * 4);
  float* c_n   = (float*)alloc((size_t)B * N * 4);
  u16*   nr    = (u16*)  alloc((size_t)B * N * H * 2);
  u16*   nrT   = (u16*)  alloc((size_t)B * H * N * 2);
  u16*   tT    = (u16*)  alloc((size_t)B * R * NB * N * 2);
  u16*   ST    = (u16*)  alloc((size_t)B * N * Q * 2);
  u16*   sq1   = (u16*)  alloc((size_t)B * Q * N * 2);
  u16*   sc2   = (u16*)  alloc((size_t)B * Q * N * 2);
  u16*   sc1T  = (u16*)  alloc((size_t)B * N * Q * 2);
  u16*   sq2   = (u16*)  alloc((size_t)B * N * Q * 2);
  u16*   P1    = (u16*)  alloc((size_t)B * Q * H * 2);
  u16*   T1T   = (u16*)  alloc((size_t)B * H * N * 2);
  u16*   Qm1   = (u16*)  alloc((size_t)B * Q * H * 2);
  u16*   P2    = (u16*)  alloc((size_t)B * N * H * 2);
  u16*   T2T   = (u16*)  alloc((size_t)B * H * Q * 2);
  u16*   Qm2   = (u16*)  alloc((size_t)B * N * H * 2);

  // 1. prep (incl. obs transpose)
  k_prep<<<6560, 256, 0, stream>>>(linW, linWb, Wb, WbB, Ww, WwB,
                                   rf, vv, obs, wC, wQ, wCQ, obsW, a_o, d_o, obsT);
  // 2. tT: nf LDS-staged once, all R in-block
  k_tt<<<dim3(N / 128, B), 512, 0, stream>>>(WbB, nf, vv, tT);
  // 3. mega RGCN (8 waves, max occupancy)
  k_rgcn<<<dim3(N / 16, B), 512, 0, stream>>>(adj, tT, WwB, rb, wC, wQ, nr, nrT, b_n, c_n);
  // 4. S in registers + row softmaxes; writes sq1, sc2, ST
  k_mm_soft<<<dim3(Q / 16, B), 512, 0, stream>>>(obsW, nr, b_n, c_n, nmask, sq1, sc2, ST);
  // 5. col softmax from ST
  k_soft_col<<<B * N, 256, 0, stream>>>(ST, a_o, d_o, omask, sc1T, sq2);
  // 6. four attention GEMMs
  GPar pP1  = {sq1,  nrT,  P1,  Q, N, (long)Q * N, (long)H * N, (long)Q * H, 0};
  GPar pT2T = {sc2,  nrT,  T2T, Q, N, (long)Q * N, (long)H * N, (long)H * Q, 1};
  GPar pT1T = {sc1T, obsT, T1T, N, Q, (long)N * Q, (long)H * Q, (long)H * N, 1};
  GPar pP2  = {sq2,  obsT, P2,  N, Q, (long)N * Q, (long)H * Q, (long)N * H, 0};
  gemm_quad8<<<dim3(N / 16, B, 4), 64, 0, stream>>>(pP1, pT2T, pT1T, pP2);
  // 7. Qm pair
  GPar pQm1 = {sq1, T1T, Qm1, Q, N, (long)Q * N, (long)H * N, (long)Q * H, 0};
  GPar pQm2 = {sq2, T2T, Qm2, N, Q, (long)N * Q, (long)H * Q, (long)N * H, 0};
  gemm_quad8<<<dim3(N / 16, B, 2), 64, 0, stream>>>(pQm1, pQm2, pQm1, pQm2);
  // 8. fused concat + output linear (both sides)
  gemm_cat2<<<dim3(N / 16, B, 2), 64, 0, stream>>>(obs, nr, P1, Qm1, P2, Qm2,
                                                   linWb, linb, outp, outp + (long)B * Q * H);

  (void)in_sizes; (void)n_in; (void)out_size; (void)ws_size;
}